// Round 12
// baseline (578.914 us; speedup 1.0000x reference)
//
#include <hip/hip_runtime.h>
#include <hip/hip_fp16.h>

// BN scale constant: 1/sqrt(1+1e-5)
#define RSQ_BN 0.9999950000374997f

typedef _Float16 f16x8 __attribute__((ext_vector_type(8)));
typedef float f32x4 __attribute__((ext_vector_type(4)));

__device__ __forceinline__ float leaky02(float x) { return x > 0.f ? x : 0.2f * x; }

__device__ __forceinline__ float4 ld4(const float* p) {
    return *reinterpret_cast<const float4*>(p);
}
__device__ __forceinline__ void st4(float* p, float4 v) {
    *reinterpret_cast<float4*>(p) = v;
}
__device__ __forceinline__ float4 h4f(uint2 u) {
    union { uint2 u; __half2 h[2]; } pk;
    pk.u = u;
    float2 lo = __half22float2(pk.h[0]);
    float2 hi = __half22float2(pk.h[1]);
    return make_float4(lo.x, lo.y, hi.x, hi.y);
}
__device__ __forceinline__ float4 f4z() { return make_float4(0.f, 0.f, 0.f, 0.f); }
__device__ __forceinline__ float4 f4bias(float4 v, float4 b) {
    return make_float4(v.x + b.x, v.y + b.y, v.z + b.z, v.w + b.w);
}
__device__ __forceinline__ float4 f4relu(float4 v) {
    return make_float4(fmaxf(v.x, 0.f), fmaxf(v.y, 0.f), fmaxf(v.z, 0.f), fmaxf(v.w, 0.f));
}
__device__ __forceinline__ float4 f4bn(float4 v, float4 g, float4 b) {
    return make_float4(v.x * g.x + b.x, v.y * g.y + b.y, v.z * g.z + b.z, v.w * g.w + b.w);
}
__device__ __forceinline__ float4 f4s(float4 v, float s) {
    return make_float4(v.x * s, v.y * s, v.z * s, v.w * s);
}

// ---------------- CSR build ----------------

__global__ void zero_i32_k(int* __restrict__ p, int n) {
    int i = blockIdx.x * 256 + threadIdx.x;
    if (i < n) p[i] = 0;
}

__global__ void hist_k(const int* __restrict__ edst, int* __restrict__ cnt, int E, int EN) {
    int i = blockIdx.x * 256 + threadIdx.x;
    if (i >= EN) return;
    int d = (i < E) ? edst[i] : (i - E);   // self-loop for i>=E
    atomicAdd(&cnt[d], 1);
}

__global__ __launch_bounds__(256)
void scanA_k(const int* __restrict__ cnt, int* __restrict__ rowptr,
             int* __restrict__ bsum, int n) {
    __shared__ int sh[256];
    int t = threadIdx.x;
    int i = blockIdx.x * 256 + t;
    int v = (i < n) ? cnt[i] : 0;
    sh[t] = v;
    __syncthreads();
#pragma unroll
    for (int off = 1; off < 256; off <<= 1) {
        int u = 0;
        if (t >= off) u = sh[t - off];
        __syncthreads();
        sh[t] += u;
        __syncthreads();
    }
    if (i < n) rowptr[i] = sh[t] - v;
    if (t == 255) bsum[blockIdx.x] = sh[255];
}

__global__ __launch_bounds__(256)
void scanB_k(int* __restrict__ bsum, int nb) {
    __shared__ int sh[256];
    int t = threadIdx.x;
    int v = (t < nb) ? bsum[t] : 0;
    sh[t] = v;
    __syncthreads();
#pragma unroll
    for (int off = 1; off < 256; off <<= 1) {
        int u = 0;
        if (t >= off) u = sh[t - off];
        __syncthreads();
        sh[t] += u;
        __syncthreads();
    }
    if (t < nb) bsum[t] = sh[t] - v;
}

__global__ __launch_bounds__(256)
void scanC_k(const int* __restrict__ cnt, const int* __restrict__ bsum,
             int* __restrict__ rowptr, int* __restrict__ cursor,
             float* __restrict__ dis, int n, int EN) {
    int i = blockIdx.x * 256 + threadIdx.x;
    if (i < n) {
        int r = rowptr[i] + bsum[blockIdx.x];
        rowptr[i] = r;
        cursor[i] = r;
        dis[i] = rsqrtf((float)cnt[i]);
    }
    if (i == 0) rowptr[n] = EN;
}

__global__ void scatter_k(const int* __restrict__ esrc, const int* __restrict__ edst,
                          int* __restrict__ cursor, int* __restrict__ colidx, int E, int EN) {
    int i = blockIdx.x * 256 + threadIdx.x;
    if (i >= EN) return;
    int s, d;
    if (i < E) { s = esrc[i]; d = edst[i]; }
    else       { s = i - E; d = s; }
    int pos = atomicAdd(&cursor[d], 1);
    colidx[pos] = s;
}

// ---------------- all-weights transpose + fp16 convert (one launch) ----------------
// dst layout [M][K] fp16 from src [K][M] fp32.

__global__ void wtx_all_k(const float* __restrict__ gcn_in_w, const float* __restrict__ gcn_res_w,
                          const float* __restrict__ gat_in_w,
                          const float* __restrict__ gcn_w, const float* __restrict__ gat_w,
                          const float* __restrict__ gcn_c1w, const float* __restrict__ gat_c1w,
                          const float* __restrict__ gcn_c3w, const float* __restrict__ gat_c3w,
                          const float* __restrict__ fin_w,
                          __half* __restrict__ WTin, __half* __restrict__ WTg,
                          __half* __restrict__ WTa, __half* __restrict__ WTc1,
                          __half* __restrict__ WTc3, __half* __restrict__ WTfin) {
    int idx = blockIdx.x * 256 + threadIdx.x;
    const float* src;
    __half* dst;
    int K, M, o;
    if (idx < 24576) {                      // 3x (64x128) input mats
        int mi = idx >> 13; o = idx & 8191;
        src = mi == 0 ? gcn_in_w : (mi == 1 ? gcn_res_w : gat_in_w);
        dst = WTin + mi * 8192; K = 64; M = 128;
    } else if (idx < 73728) {               // 3x (128x128) gcn layer mats
        int r = idx - 24576; int mi = r >> 14; o = r & 16383;
        src = gcn_w + mi * 16384; dst = WTg + mi * 16384; K = 128; M = 128;
    } else if (idx < 122880) {              // 3x (128x128) gat layer mats
        int r = idx - 73728; int mi = r >> 14; o = r & 16383;
        src = gat_w + mi * 16384; dst = WTa + mi * 16384; K = 128; M = 128;
    } else if (idx < 139264) {              // 2x (128x64) c1 mats
        int r = idx - 122880; int mi = r >> 13; o = r & 8191;
        src = mi ? gat_c1w : gcn_c1w; dst = WTc1 + mi * 8192; K = 128; M = 64;
    } else if (idx < 147456) {              // 2x (32x128) c3 mats
        int r = idx - 139264; int mi = r >> 12; o = r & 4095;
        src = mi ? gat_c3w : gcn_c3w; dst = WTc3 + mi * 4096; K = 32; M = 128;
    } else if (idx < 155648) {              // fin (128x64)
        o = idx - 147456; src = fin_w; dst = WTfin; K = 128; M = 64;
    } else return;
    int mcol = o / K, k = o - mcol * K;
    dst[o] = (__half)src[k * M + mcol];
}

// ---------------- fp32 GEMM helper (only the tiny 64->32 tail keeps it) ----------------

#define FMA4R(A_, xv, w0, w1, w2, w3)                                  \
    A_.x += xv.x * w0.x + xv.y * w1.x + xv.z * w2.x + xv.w * w3.x;     \
    A_.y += xv.x * w0.y + xv.y * w1.y + xv.z * w2.y + xv.w * w3.y;     \
    A_.z += xv.x * w0.z + xv.y * w1.z + xv.z * w2.z + xv.w * w3.z;     \
    A_.w += xv.x * w0.w + xv.y * w1.w + xv.z * w2.w + xv.w * w3.w;

template <int K, int M>
__device__ __forceinline__ void gemm4(const float* __restrict__ Ws,
                                      const float* xa, const float* xb,
                                      const float* xc, const float* xd, int c,
                                      float4& A, float4& B, float4& C, float4& D) {
#pragma unroll 4
    for (int k = 0; k < K; k += 4) {
        float4 va = ld4(xa + k), vb = ld4(xb + k), vc = ld4(xc + k), vd = ld4(xd + k);
        const float* wp = Ws + k * M + c;
        float4 w0 = ld4(wp), w1 = ld4(wp + M), w2 = ld4(wp + 2 * M), w3 = ld4(wp + 3 * M);
        FMA4R(A, va, w0, w1, w2, w3)
        FMA4R(B, vb, w0, w1, w2, w3)
        FMA4R(C, vc, w0, w1, w2, w3)
        FMA4R(D, vd, w0, w1, w2, w3)
    }
}

template <int K, int M>
__global__ __launch_bounds__(256)
void tail2_k(const float* __restrict__ X0, const float* __restrict__ W0, const float* __restrict__ b0,
             float* __restrict__ Y0,
             const float* __restrict__ X1, const float* __restrict__ W1, const float* __restrict__ b1,
             float* __restrict__ Y1,
             int n, int gper, int do_relu) {
    constexpr int CG = M / 4, RPB = 256 / CG;
    bool s1 = blockIdx.x >= gper;
    int blk = s1 ? blockIdx.x - gper : blockIdx.x;
    const float* X = s1 ? X1 : X0;
    const float* W = s1 ? W1 : W0;
    const float* bi = s1 ? b1 : b0;
    float* Y = s1 ? Y1 : Y0;
    __shared__ float Ws[K * M];
    for (int i = threadIdx.x; i < K * M; i += 256) Ws[i] = W[i];
    __syncthreads();
    int cg = threadIdx.x % CG, r = threadIdx.x / CG, c = cg * 4;
    int ra = blk * (4 * RPB) + r, rb = ra + RPB, rc = ra + 2 * RPB, rd = ra + 3 * RPB;
    const float* xa = X + (size_t)(ra < n ? ra : 0) * K;
    const float* xb = X + (size_t)(rb < n ? rb : 0) * K;
    const float* xc = X + (size_t)(rc < n ? rc : 0) * K;
    const float* xd = X + (size_t)(rd < n ? rd : 0) * K;
    float4 A = f4z(), B = f4z(), C = f4z(), D = f4z();
    gemm4<K, M>(Ws, xa, xb, xc, xd, c, A, B, C, D);
    float4 bv = ld4(bi + c);
    A = f4bias(A, bv); B = f4bias(B, bv); C = f4bias(C, bv); D = f4bias(D, bv);
    if (do_relu) { A = f4relu(A); B = f4relu(B); C = f4relu(C); D = f4relu(D); }
    if (ra < n) st4(Y + (size_t)ra * M + c, A);
    if (rb < n) st4(Y + (size_t)rb * M + c, B);
    if (rc < n) st4(Y + (size_t)rc * M + c, C);
    if (rd < n) st4(Y + (size_t)rd * M + c, D);
}

// ---------------- MFMA dense kernels ----------------

__device__ __forceinline__ f16x8 mk_af(const float* xr, int kb) {
    float4 v0 = ld4(xr + kb), v1 = ld4(xr + kb + 4);
    f16x8 af;
    af[0] = (_Float16)v0.x; af[1] = (_Float16)v0.y;
    af[2] = (_Float16)v0.z; af[3] = (_Float16)v0.w;
    af[4] = (_Float16)v1.x; af[5] = (_Float16)v1.y;
    af[6] = (_Float16)v1.z; af[7] = (_Float16)v1.w;
    return af;
}

// input stage: 3 weight sets, same X (K=64, M=128), bias only, fp32 out
__global__ __launch_bounds__(256)
void mfma_lin3_k(const float* __restrict__ X, const __half* __restrict__ WTin,
                 const float* __restrict__ b0, float* __restrict__ Y0,
                 const float* __restrict__ b1, float* __restrict__ Y1,
                 const float* __restrict__ b2, float* __restrict__ Y2,
                 int n, int gper) {
    constexpr int K = 64, CT = 8;
    int set = blockIdx.x / gper, blk = blockIdx.x % gper;
    const __half* WT = WTin + (size_t)set * 8192;
    const float* bi = set == 0 ? b0 : (set == 1 ? b1 : b2);
    float* Y = set == 0 ? Y0 : (set == 1 ? Y1 : Y2);
    int wave = threadIdx.x >> 6, lane = threadIdx.x & 63;
    int m = lane & 15, quad = lane >> 4;
    int row0 = blk * 64 + wave * 16;
    int arow = min(row0 + m, n - 1);
    const float* xr = X + (size_t)arow * K;
    f32x4 acc[CT];
#pragma unroll
    for (int ct = 0; ct < CT; ++ct) acc[ct] = (f32x4){0.f, 0.f, 0.f, 0.f};
#pragma unroll
    for (int k32 = 0; k32 < K / 32; ++k32) {
        int kb = k32 * 32 + quad * 8;
        f16x8 af = mk_af(xr, kb);
#pragma unroll
        for (int ct = 0; ct < CT; ++ct) {
            f16x8 bf = *reinterpret_cast<const f16x8*>(WT + (size_t)(ct * 16 + m) * K + kb);
            acc[ct] = __builtin_amdgcn_mfma_f32_16x16x32_f16(af, bf, acc[ct], 0, 0, 0);
        }
    }
#pragma unroll
    for (int ct = 0; ct < CT; ++ct) {
        int col = ct * 16 + m;
        float cb = bi[col];
#pragma unroll
        for (int reg = 0; reg < 4; ++reg) {
            int row = row0 + quad * 4 + reg;
            if (row < n) Y[(size_t)row * 128 + col] = acc[ct][reg] + cb;
        }
    }
}

// tail pair: two (X, WT, b[,bn]) sets, fp32 out
template <int K, int M>
__global__ __launch_bounds__(256)
void mfma_lin2_k(const float* __restrict__ X0, const __half* __restrict__ WT0,
                 const float* __restrict__ b0, const float* __restrict__ g0,
                 const float* __restrict__ bb0, float* __restrict__ Y0,
                 const float* __restrict__ X1, const __half* __restrict__ WT1,
                 const float* __restrict__ b1, const float* __restrict__ g1,
                 const float* __restrict__ bb1, float* __restrict__ Y1,
                 int n, int gper, int do_relu) {
    constexpr int CT = M / 16;
    bool s1 = blockIdx.x >= gper;
    int blk = s1 ? blockIdx.x - gper : blockIdx.x;
    const float* X = s1 ? X1 : X0;
    const __half* WT = s1 ? WT1 : WT0;
    const float* bi = s1 ? b1 : b0;
    const float* bg = s1 ? g1 : g0;
    const float* bb = s1 ? bb1 : bb0;
    float* Y = s1 ? Y1 : Y0;
    int wave = threadIdx.x >> 6, lane = threadIdx.x & 63;
    int m = lane & 15, quad = lane >> 4;
    int row0 = blk * 64 + wave * 16;
    int arow = min(row0 + m, n - 1);
    const float* xr = X + (size_t)arow * K;
    f32x4 acc[CT];
#pragma unroll
    for (int ct = 0; ct < CT; ++ct) acc[ct] = (f32x4){0.f, 0.f, 0.f, 0.f};
#pragma unroll
    for (int k32 = 0; k32 < K / 32; ++k32) {
        int kb = k32 * 32 + quad * 8;
        f16x8 af = mk_af(xr, kb);
#pragma unroll
        for (int ct = 0; ct < CT; ++ct) {
            f16x8 bf = *reinterpret_cast<const f16x8*>(WT + (size_t)(ct * 16 + m) * K + kb);
            acc[ct] = __builtin_amdgcn_mfma_f32_16x16x32_f16(af, bf, acc[ct], 0, 0, 0);
        }
    }
#pragma unroll
    for (int ct = 0; ct < CT; ++ct) {
        int col = ct * 16 + m;
        float cb = bi[col];
        float cg = bg ? bg[col] * RSQ_BN : 1.f;
        float cbb = bg ? bb[col] : 0.f;
#pragma unroll
        for (int reg = 0; reg < 4; ++reg) {
            int row = row0 + quad * 4 + reg;
            if (row < n) {
                float v = acc[ct][reg] + cb;
                if (do_relu) v = fmaxf(v, 0.f);
                if (bg) v = v * cg + cbb;
                Y[(size_t)row * M + col] = v;
            }
        }
    }
}

// final: blend(0.6*XA+0.4*XB) @ fin(K=128,M=64) -> relu -> bn -> @fin2 -> out[n,2]
__global__ __launch_bounds__(256)
void mfma_linF_k(const float* __restrict__ XA, const float* __restrict__ XB,
                 const __half* __restrict__ WT, const float* __restrict__ bi,
                 const float* __restrict__ bg, const float* __restrict__ bb,
                 const float* __restrict__ w2, const float* __restrict__ b2,
                 float* __restrict__ out, int n) {
    constexpr int K = 128, M = 64, CT = 4;
    int wave = threadIdx.x >> 6, lane = threadIdx.x & 63;
    int m = lane & 15, quad = lane >> 4;
    int row0 = blockIdx.x * 64 + wave * 16;
    int arow = min(row0 + m, n - 1);
    const float* xra = XA + (size_t)arow * K;
    const float* xrb = XB + (size_t)arow * K;
    f32x4 acc[CT];
#pragma unroll
    for (int ct = 0; ct < CT; ++ct) acc[ct] = (f32x4){0.f, 0.f, 0.f, 0.f};
#pragma unroll
    for (int k32 = 0; k32 < K / 32; ++k32) {
        int kb = k32 * 32 + quad * 8;
        float4 a0 = ld4(xra + kb), a1 = ld4(xra + kb + 4);
        float4 u0 = ld4(xrb + kb), u1 = ld4(xrb + kb + 4);
        f16x8 af;
        af[0] = (_Float16)(0.6f * a0.x + 0.4f * u0.x);
        af[1] = (_Float16)(0.6f * a0.y + 0.4f * u0.y);
        af[2] = (_Float16)(0.6f * a0.z + 0.4f * u0.z);
        af[3] = (_Float16)(0.6f * a0.w + 0.4f * u0.w);
        af[4] = (_Float16)(0.6f * a1.x + 0.4f * u1.x);
        af[5] = (_Float16)(0.6f * a1.y + 0.4f * u1.y);
        af[6] = (_Float16)(0.6f * a1.z + 0.4f * u1.z);
        af[7] = (_Float16)(0.6f * a1.w + 0.4f * u1.w);
#pragma unroll
        for (int ct = 0; ct < CT; ++ct) {
            f16x8 bf = *reinterpret_cast<const f16x8*>(WT + (size_t)(ct * 16 + m) * K + kb);
            acc[ct] = __builtin_amdgcn_mfma_f32_16x16x32_f16(af, bf, acc[ct], 0, 0, 0);
        }
    }
    float p0[4] = {0.f, 0.f, 0.f, 0.f}, p1[4] = {0.f, 0.f, 0.f, 0.f};
#pragma unroll
    for (int ct = 0; ct < CT; ++ct) {
        int col = ct * 16 + m;
        float cb = bi[col];
        float cg = bg[col] * RSQ_BN;
        float cbb = bb[col];
        float w20 = w2[2 * col], w21 = w2[2 * col + 1];
#pragma unroll
        for (int reg = 0; reg < 4; ++reg) {
            float v = fmaxf(acc[ct][reg] + cb, 0.f) * cg + cbb;
            p0[reg] += v * w20;
            p1[reg] += v * w21;
        }
    }
    for (int off = 1; off < 16; off <<= 1) {
#pragma unroll
        for (int reg = 0; reg < 4; ++reg) {
            p0[reg] += __shfl_xor(p0[reg], off);
            p1[reg] += __shfl_xor(p1[reg], off);
        }
    }
    if (m == 0) {
#pragma unroll
        for (int reg = 0; reg < 4; ++reg) {
            int row = row0 + quad * 4 + reg;
            if (row < n) {
                out[row * 2] = p0[reg] + b2[0];
                out[row * 2 + 1] = p1[reg] + b2[1];
            }
        }
    }
}

// ---------------- per-layer pair GEMM via MFMA (gcn dis-fold + gat attn dots) ----------------

__global__ __launch_bounds__(256)
void dual128_mfma_k(const float* __restrict__ Xg, const __half* __restrict__ WTg,
                    __half* __restrict__ Yg,
                    const float* __restrict__ Xa, const __half* __restrict__ WTa,
                    __half* __restrict__ Ya,
                    const float* __restrict__ dis,
                    const float* __restrict__ asrc, const float* __restrict__ adst,
                    float* __restrict__ avp, float* __restrict__ bvp,
                    int hh, int n, int gper) {
    bool gat = blockIdx.x >= gper;
    int blk = gat ? blockIdx.x - gper : blockIdx.x;
    const float* X = gat ? Xa : Xg;
    const __half* WT = gat ? WTa : WTg;
    __half* Y = gat ? Ya : Yg;
    int wave = threadIdx.x >> 6;
    int lane = threadIdx.x & 63;
    int m = lane & 15, quad = lane >> 4;
    int row0 = blk * 64 + wave * 16;
    int arow = min(row0 + m, n - 1);
    const float* xr = X + (size_t)arow * 128;
    f32x4 acc[8];
#pragma unroll
    for (int ct = 0; ct < 8; ++ct) acc[ct] = (f32x4){0.f, 0.f, 0.f, 0.f};
#pragma unroll
    for (int k32 = 0; k32 < 4; ++k32) {
        int kb = k32 * 32 + quad * 8;
        f16x8 af = mk_af(xr, kb);
#pragma unroll
        for (int ct = 0; ct < 8; ++ct) {
            f16x8 bf = *reinterpret_cast<const f16x8*>(WT + (size_t)(ct * 16 + m) * 128 + kb);
            acc[ct] = __builtin_amdgcn_mfma_f32_16x16x32_f16(af, bf, acc[ct], 0, 0, 0);
        }
    }
    if (!gat) {
#pragma unroll
        for (int reg = 0; reg < 4; ++reg) {
            int row = row0 + quad * 4 + reg;
            if (row < n) {
                float dv = dis[row];
#pragma unroll
                for (int ct = 0; ct < 8; ++ct)
                    Y[(size_t)row * 128 + ct * 16 + m] = (__half)(acc[ct][reg] * dv);
            }
        }
    } else {
        float cas[8], cad[8];
#pragma unroll
        for (int ct = 0; ct < 8; ++ct) {
            cas[ct] = asrc[ct * 16 + m];
            cad[ct] = adst[ct * 16 + m];
        }
        int ctph = 8 / hh;   // col-tiles per head
#pragma unroll
        for (int reg = 0; reg < 4; ++reg) {
            int row = row0 + quad * 4 + reg;
            bool valid = row < n;
            if (valid) {
#pragma unroll
                for (int ct = 0; ct < 8; ++ct)
                    Y[(size_t)row * 128 + ct * 16 + m] = (__half)acc[ct][reg];
            }
            for (int h = 0; h < hh; ++h) {
                float sa = 0.f, sd = 0.f;
                for (int j = 0; j < ctph; ++j) {
                    int ct = h * ctph + j;
                    sa += acc[ct][reg] * cas[ct];
                    sd += acc[ct][reg] * cad[ct];
                }
                for (int off = 1; off < 16; off <<= 1) {
                    sa += __shfl_xor(sa, off);
                    sd += __shfl_xor(sd, off);
                }
                if (m == 0 && valid) {
                    avp[row * hh + h] = sa;
                    bvp[row * hh + h] = sd;
                }
            }
        }
    }
}

// ---------------- fused sparse aggregation, XCD column-sliced ----------------
// Block = 64 nodes x 32-col quarter (4 lanes/node x 8 cols per table).
// quarter = blockIdx & 3 -> with round-robin block->XCD dispatch, each quarter
// runs on XCDs {q, q+4}: per-XCD L2 working set = both tables' quarter ~ 3.85 MB < 4 MB.

__global__ __launch_bounds__(256)
void fused_gather_k(const int* __restrict__ rowptr, const int* __restrict__ colidx,
                    const float* __restrict__ dis,
                    const __half* __restrict__ Tg, const float* __restrict__ gbias,
                    const float* __restrict__ gbng, const float* __restrict__ gbnb,
                    const float* __restrict__ res, float* __restrict__ Yg,
                    const __half* __restrict__ Ta, const float* __restrict__ avp,
                    const float* __restrict__ bvp, const float* __restrict__ abias,
                    const float* __restrict__ abng, const float* __restrict__ abnb,
                    const float* __restrict__ fimp, float* __restrict__ Ya,
                    int n, int hh, int log2C) {
    int q = blockIdx.x & 3;                 // column quarter -> XCD affinity
    int nb = blockIdx.x >> 2;               // node tile
    int i = nb * 64 + (threadIdx.x >> 2);
    if (i >= n) return;
    int c = q * 32 + (threadIdx.x & 3) * 8;
    int h = c >> log2C;
    float ad = bvp[i * hh + h];
    int p0 = rowptr[i], p1 = rowptr[i + 1];
    float4 glo = f4z(), ghi = f4z();           // gcn accumulators (plain sum)
    float4 alo = f4z(), ahi = f4z();           // gat accumulators (online softmax)
    float m = -3.0e38f, s = 0.f;

#define GACC(qq)                                                                \
    {                                                                           \
        float4 t0 = h4f(make_uint2(qq.x, qq.y)), t1 = h4f(make_uint2(qq.z, qq.w)); \
        glo.x += t0.x; glo.y += t0.y; glo.z += t0.z; glo.w += t0.w;             \
        ghi.x += t1.x; ghi.y += t1.y; ghi.z += t1.z; ghi.w += t1.w;             \
    }
#define AACC(qq, ww)                                                            \
    {                                                                           \
        float4 t0 = h4f(make_uint2(qq.x, qq.y)), t1 = h4f(make_uint2(qq.z, qq.w)); \
        alo.x += t0.x * ww; alo.y += t0.y * ww; alo.z += t0.z * ww; alo.w += t0.w * ww; \
        ahi.x += t1.x * ww; ahi.y += t1.y * ww; ahi.z += t1.z * ww; ahi.w += t1.w * ww; \
    }

    int p = p0;
    for (; p + 4 <= p1; p += 4) {
        int sx[4]; float e[4]; uint4 qg[4], qa[4];
#pragma unroll
        for (int j = 0; j < 4; ++j) sx[j] = colidx[p + j];
#pragma unroll
        for (int j = 0; j < 4; ++j) e[j] = leaky02(avp[sx[j] * hh + h] + ad);
#pragma unroll
        for (int j = 0; j < 4; ++j)
            qg[j] = *reinterpret_cast<const uint4*>(Tg + (size_t)sx[j] * 128 + c);
#pragma unroll
        for (int j = 0; j < 4; ++j)
            qa[j] = *reinterpret_cast<const uint4*>(Ta + (size_t)sx[j] * 128 + c);
#pragma unroll
        for (int j = 0; j < 4; ++j) GACC(qg[j])
        float mc = fmaxf(fmaxf(e[0], e[1]), fmaxf(e[2], e[3]));
        float mn = fmaxf(m, mc);
        float scale = expf(m - mn);
        alo = f4s(alo, scale);
        ahi = f4s(ahi, scale);
        float wsum = 0.f;
#pragma unroll
        for (int j = 0; j < 4; ++j) {
            float wj = expf(e[j] - mn);
            wsum += wj;
            AACC(qa[j], wj)
        }
        s = s * scale + wsum;
        m = mn;
    }
    for (; p < p1; ++p) {
        int s0 = colidx[p];
        float e0 = leaky02(avp[s0 * hh + h] + ad);
        uint4 qg0 = *reinterpret_cast<const uint4*>(Tg + (size_t)s0 * 128 + c);
        uint4 qa0 = *reinterpret_cast<const uint4*>(Ta + (size_t)s0 * 128 + c);
        GACC(qg0)
        float mn = fmaxf(m, e0);
        float scale = expf(m - mn);
        float w0 = expf(e0 - mn);
        s = s * scale + w0;
        alo = f4s(alo, scale);
        ahi = f4s(ahi, scale);
        AACC(qa0, w0)
        m = mn;
    }

    // ---- GCN epilogue ----
    {
        float di = dis[i];
        float4 b0 = ld4(gbias + c), b1 = ld4(gbias + c + 4);
        glo = make_float4(glo.x * di + b0.x, glo.y * di + b0.y, glo.z * di + b0.z, glo.w * di + b0.w);
        ghi = make_float4(ghi.x * di + b1.x, ghi.y * di + b1.y, ghi.z * di + b1.z, ghi.w * di + b1.w);
        float4 g0 = ld4(gbng + c), g1 = ld4(gbng + c + 4);
        g0 = f4s(g0, RSQ_BN); g1 = f4s(g1, RSQ_BN);
        float4 h0 = ld4(gbnb + c), h1 = ld4(gbnb + c + 4);
        glo = f4relu(f4bn(glo, g0, h0));
        ghi = f4relu(f4bn(ghi, g1, h1));
        if (res) {
            float4 r0 = ld4(res + (size_t)i * 128 + c), r1 = ld4(res + (size_t)i * 128 + c + 4);
            glo = f4bias(glo, r0); ghi = f4bias(ghi, r1);
        }
        st4(Yg + (size_t)i * 128 + c, glo);
        st4(Yg + (size_t)i * 128 + c + 4, ghi);
    }
    // ---- GAT epilogue ----
    {
        float si = 1.f / (s + 1e-16f);
        float4 b0 = ld4(abias + c), b1 = ld4(abias + c + 4);
        alo = make_float4(alo.x * si + b0.x, alo.y * si + b0.y, alo.z * si + b0.z, alo.w * si + b0.w);
        ahi = make_float4(ahi.x * si + b1.x, ahi.y * si + b1.y, ahi.z * si + b1.z, ahi.w * si + b1.w);
        float4 g0 = ld4(abng + c), g1 = ld4(abng + c + 4);
        g0 = f4s(g0, RSQ_BN); g1 = f4s(g1, RSQ_BN);
        float4 h0 = ld4(abnb + c), h1 = ld4(abnb + c + 4);
        alo = f4bn(alo, g0, h0);
        ahi = f4bn(ahi, g1, h1);
        alo.x = alo.x > 0.f ? alo.x : expm1f(alo.x);
        alo.y = alo.y > 0.f ? alo.y : expm1f(alo.y);
        alo.z = alo.z > 0.f ? alo.z : expm1f(alo.z);
        alo.w = alo.w > 0.f ? alo.w : expm1f(alo.w);
        ahi.x = ahi.x > 0.f ? ahi.x : expm1f(ahi.x);
        ahi.y = ahi.y > 0.f ? ahi.y : expm1f(ahi.y);
        ahi.z = ahi.z > 0.f ? ahi.z : expm1f(ahi.z);
        ahi.w = ahi.w > 0.f ? ahi.w : expm1f(ahi.w);
        if (fimp) {
            float4 f0 = ld4(fimp + c), f1 = ld4(fimp + c + 4);
            alo = make_float4(alo.x * f0.x, alo.y * f0.y, alo.z * f0.z, alo.w * f0.w);
            ahi = make_float4(ahi.x * f1.x, ahi.y * f1.y, ahi.z * f1.z, ahi.w * f1.w);
        }
        st4(Ya + (size_t)i * 128 + c, alo);
        st4(Ya + (size_t)i * 128 + c + 4, ahi);
    }
#undef GACC
#undef AACC
}

// ---------------- host orchestration ----------------

static inline int cdiv(int a, int b) { return (a + b - 1) / b; }

extern "C" void kernel_launch(void* const* d_in, const int* in_sizes, int n_in,
                              void* d_out, int out_size, void* d_ws, size_t ws_size,
                              hipStream_t stream) {
    const float* x       = (const float*)d_in[0];
    const int*   ei      = (const int*)d_in[1];
    const float* gcn_in_w = (const float*)d_in[2];
    const float* gcn_in_b = (const float*)d_in[3];
    const float* gcn_res_w = (const float*)d_in[4];
    const float* gcn_res_b = (const float*)d_in[5];
    const float* gcn_w   = (const float*)d_in[6];
    const float* gcn_b   = (const float*)d_in[7];
    const float* gcn_bn_g = (const float*)d_in[8];
    const float* gcn_bn_b = (const float*)d_in[9];
    const float* gcn_c1w = (const float*)d_in[10];
    const float* gcn_c1b = (const float*)d_in[11];
    const float* gcn_c2w = (const float*)d_in[12];
    const float* gcn_c2b = (const float*)d_in[13];
    const float* gcn_c3w = (const float*)d_in[14];
    const float* gcn_c3b = (const float*)d_in[15];
    const float* gat_in_w = (const float*)d_in[16];
    const float* gat_in_b = (const float*)d_in[17];
    const float* gat_w   = (const float*)d_in[18];
    const float* gat_asrc = (const float*)d_in[19];
    const float* gat_adst = (const float*)d_in[20];
    const float* gat_b   = (const float*)d_in[21];
    const float* gat_bn_g = (const float*)d_in[22];
    const float* gat_bn_b = (const float*)d_in[23];
    const float* feat_imp = (const float*)d_in[24];
    const float* gat_c1w = (const float*)d_in[25];
    const float* gat_c1b = (const float*)d_in[26];
    const float* gat_cbn_g = (const float*)d_in[27];
    const float* gat_cbn_b = (const float*)d_in[28];
    const float* gat_c2w = (const float*)d_in[29];
    const float* gat_c2b = (const float*)d_in[30];
    const float* gat_c3w = (const float*)d_in[31];
    const float* gat_c3b = (const float*)d_in[32];
    const float* fin_w   = (const float*)d_in[33];
    const float* fin_b   = (const float*)d_in[34];
    const float* fin_bn_g = (const float*)d_in[35];
    const float* fin_bn_b = (const float*)d_in[36];
    const float* fin2_w  = (const float*)d_in[37];
    const float* fin2_b  = (const float*)d_in[38];

    const int N = in_sizes[0] / 64;
    const int E = in_sizes[1] / 2;
    const int EN = E + N;
    const int* esrc = ei;
    const int* edst = ei + E;

    // workspace carve (256B aligned)
    char* wp = (char*)d_ws;
    auto alloc = [&](size_t bytes) -> void* {
        void* p = (void*)wp;
        wp += (bytes + 255) & ~(size_t)255;
        return p;
    };
    int* cnt    = (int*)alloc((size_t)N * 4);
    int* rowptr = (int*)alloc((size_t)(N + 1) * 4);
    int* cursor = (int*)alloc((size_t)N * 4);
    int* bsum   = (int*)alloc((size_t)256 * 4);
    int* colidx = (int*)alloc((size_t)EN * 4);
    float* dis  = (float*)alloc((size_t)N * 4);
    float* A    = (float*)alloc((size_t)N * 128 * 4);   // gcn ping / GOUT reuse
    float* B    = (float*)alloc((size_t)N * 128 * 4);   // gcn pong
    float* G    = (float*)alloc((size_t)N * 128 * 4);   // gat ping / AOUT reuse
    float* H    = (float*)alloc((size_t)N * 128 * 4);   // gat pong
    float* R    = (float*)alloc((size_t)N * 128 * 4);   // gcn residual
    __half* Th1 = (__half*)alloc((size_t)N * 128 * 2);  // aliased as h1g after layers
    __half* Th2 = (__half*)alloc((size_t)N * 128 * 2);  // aliased as h1a after layers
    float* h2g  = (float*)alloc((size_t)N * 32 * 4);
    float* h2a  = (float*)alloc((size_t)N * 32 * 4);
    float* avv  = (float*)alloc((size_t)N * 4 * 4);
    float* bvv  = (float*)alloc((size_t)N * 4 * 4);
    __half* WTin = (__half*)alloc((size_t)3 * 8192 * 2);
    __half* WTg  = (__half*)alloc((size_t)3 * 16384 * 2);
    __half* WTa  = (__half*)alloc((size_t)3 * 16384 * 2);
    __half* WTc1 = (__half*)alloc((size_t)2 * 8192 * 2);
    __half* WTc3 = (__half*)alloc((size_t)2 * 4096 * 2);
    __half* WTfin = (__half*)alloc((size_t)8192 * 2);
    float* h1g = (float*)Th1;   // N*64*4 == N*128*2 bytes
    float* h1a = (float*)Th2;

    // ---- CSR build + all-weight transpose ----
    const int nScanB = cdiv(N, 256);
    zero_i32_k<<<cdiv(N, 256), 256, 0, stream>>>(cnt, N);
    hist_k<<<cdiv(EN, 256), 256, 0, stream>>>(edst, cnt, E, EN);
    scanA_k<<<nScanB, 256, 0, stream>>>(cnt, rowptr, bsum, N);
    scanB_k<<<1, 256, 0, stream>>>(bsum, nScanB);
    scanC_k<<<nScanB, 256, 0, stream>>>(cnt, bsum, rowptr, cursor, dis, N, EN);
    scatter_k<<<cdiv(EN, 256), 256, 0, stream>>>(esrc, edst, cursor, colidx, E, EN);
    wtx_all_k<<<608, 256, 0, stream>>>(gcn_in_w, gcn_res_w, gat_in_w, gcn_w, gat_w,
                                       gcn_c1w, gat_c1w, gcn_c3w, gat_c3w, fin_w,
                                       WTin, WTg, WTa, WTc1, WTc3, WTfin);

    const int g64r  = cdiv(N, 64);    // mfma kernels: 64 rows/block
    const int g128r = cdiv(N, 128);   // fp32 tail M=32
    const int gGq   = cdiv(N, 64) * 4; // gather: 64 nodes x 4 column-quarters

    // ---- input stage: gcn_in -> A, gcn_res -> R, gat_in -> G ----
    mfma_lin3_k<<<3 * g64r, 256, 0, stream>>>(x, WTin, gcn_in_b, A, gcn_res_b, R,
                                              gat_in_b, G, N, g64r);

    // ---- 3 layers, both branches in lockstep ----
    const int heads_arr[3] = {4, 4, 1};
    float* gcur = A; float* gnxt = B;
    float* acur = G; float* anxt = H;
    for (int i = 0; i < 3; ++i) {
        int hh = heads_arr[i];
        int log2C = (hh == 4) ? 5 : 7;
        dual128_mfma_k<<<2 * g64r, 256, 0, stream>>>(gcur, WTg + (size_t)i * 16384, Th1,
                                                     acur, WTa + (size_t)i * 16384, Th2, dis,
                                                     gat_asrc + i * 128, gat_adst + i * 128,
                                                     avv, bvv, hh, N, g64r);
        fused_gather_k<<<gGq, 256, 0, stream>>>(rowptr, colidx, dis,
                                                Th1, gcn_b + i * 128, gcn_bn_g + i * 128,
                                                gcn_bn_b + i * 128, (i == 1) ? R : nullptr, gnxt,
                                                Th2, avv, bvv, gat_b + i * 128,
                                                gat_bn_g + i * 128, gat_bn_b + i * 128,
                                                (i == 2) ? feat_imp : nullptr, anxt,
                                                N, hh, log2C);
        float* t = gcur; gcur = gnxt; gnxt = t;
        t = acur; acur = anxt; anxt = t;
    }
    // gcur = gcn final xp (B), acur = gat final xg (H)

    // ---- MLP tails ----  (h1g/h1a alias Th1/Th2 — Th no longer needed)
    mfma_lin2_k<128, 64><<<2 * g64r, 256, 0, stream>>>(
        gcur, WTc1, gcn_c1b, nullptr, nullptr, h1g,
        acur, WTc1 + 8192, gat_c1b, gat_cbn_g, gat_cbn_b, h1a, N, g64r, 1);
    tail2_k<64, 32><<<2 * g128r, 256, 0, stream>>>(
        h1g, gcn_c2w, gcn_c2b, h2g,
        h1a, gat_c2w, gat_c2b, h2a, N, g128r, 1);
    mfma_lin2_k<32, 128><<<2 * g64r, 256, 0, stream>>>(
        h2g, WTc3, gcn_c3b, nullptr, nullptr, A,
        h2a, WTc3 + 4096, gat_c3b, nullptr, nullptr, G, N, g64r, 0);

    // ---- fusion tail: blend + fin linear + bn + classifier ----
    mfma_linF_k<<<g64r, 256, 0, stream>>>(A, G, WTfin, fin_b, fin_bn_g, fin_bn_b,
                                          fin2_w, fin2_b, (float*)d_out, N);
}

// Round 13
// 569.060 us; speedup vs baseline: 1.0173x; 1.0173x over previous
//
#include <hip/hip_runtime.h>
#include <hip/hip_fp16.h>

// BN scale constant: 1/sqrt(1+1e-5)
#define RSQ_BN 0.9999950000374997f

typedef _Float16 f16x8 __attribute__((ext_vector_type(8)));
typedef float f32x4 __attribute__((ext_vector_type(4)));

__device__ __forceinline__ float leaky02(float x) { return x > 0.f ? x : 0.2f * x; }

__device__ __forceinline__ float4 ld4(const float* p) {
    return *reinterpret_cast<const float4*>(p);
}
__device__ __forceinline__ void st4(float* p, float4 v) {
    *reinterpret_cast<float4*>(p) = v;
}
__device__ __forceinline__ float4 h4f(uint2 u) {
    union { uint2 u; __half2 h[2]; } pk;
    pk.u = u;
    float2 lo = __half22float2(pk.h[0]);
    float2 hi = __half22float2(pk.h[1]);
    return make_float4(lo.x, lo.y, hi.x, hi.y);
}
__device__ __forceinline__ float4 f4z() { return make_float4(0.f, 0.f, 0.f, 0.f); }
__device__ __forceinline__ float4 f4bias(float4 v, float4 b) {
    return make_float4(v.x + b.x, v.y + b.y, v.z + b.z, v.w + b.w);
}
__device__ __forceinline__ float4 f4relu(float4 v) {
    return make_float4(fmaxf(v.x, 0.f), fmaxf(v.y, 0.f), fmaxf(v.z, 0.f), fmaxf(v.w, 0.f));
}
__device__ __forceinline__ float4 f4bn(float4 v, float4 g, float4 b) {
    return make_float4(v.x * g.x + b.x, v.y * g.y + b.y, v.z * g.z + b.z, v.w * g.w + b.w);
}
__device__ __forceinline__ float4 f4s(float4 v, float s) {
    return make_float4(v.x * s, v.y * s, v.z * s, v.w * s);
}

// ---------------- CSR build ----------------

__global__ void zero_i32_k(int* __restrict__ p, int n) {
    int i = blockIdx.x * 256 + threadIdx.x;
    if (i < n) p[i] = 0;
}

__global__ void hist_k(const int* __restrict__ edst, int* __restrict__ cnt, int E, int EN) {
    int i = blockIdx.x * 256 + threadIdx.x;
    if (i >= EN) return;
    int d = (i < E) ? edst[i] : (i - E);   // self-loop for i>=E
    atomicAdd(&cnt[d], 1);
}

__global__ __launch_bounds__(256)
void scanA_k(const int* __restrict__ cnt, int* __restrict__ rowptr,
             int* __restrict__ bsum, int n) {
    __shared__ int sh[256];
    int t = threadIdx.x;
    int i = blockIdx.x * 256 + t;
    int v = (i < n) ? cnt[i] : 0;
    sh[t] = v;
    __syncthreads();
#pragma unroll
    for (int off = 1; off < 256; off <<= 1) {
        int u = 0;
        if (t >= off) u = sh[t - off];
        __syncthreads();
        sh[t] += u;
        __syncthreads();
    }
    if (i < n) rowptr[i] = sh[t] - v;
    if (t == 255) bsum[blockIdx.x] = sh[255];
}

__global__ __launch_bounds__(256)
void scanB_k(int* __restrict__ bsum, int nb) {
    __shared__ int sh[256];
    int t = threadIdx.x;
    int v = (t < nb) ? bsum[t] : 0;
    sh[t] = v;
    __syncthreads();
#pragma unroll
    for (int off = 1; off < 256; off <<= 1) {
        int u = 0;
        if (t >= off) u = sh[t - off];
        __syncthreads();
        sh[t] += u;
        __syncthreads();
    }
    if (t < nb) bsum[t] = sh[t] - v;
}

__global__ __launch_bounds__(256)
void scanC_k(const int* __restrict__ cnt, const int* __restrict__ bsum,
             int* __restrict__ rowptr, int* __restrict__ cursor,
             float* __restrict__ dis, int n, int EN) {
    int i = blockIdx.x * 256 + threadIdx.x;
    if (i < n) {
        int r = rowptr[i] + bsum[blockIdx.x];
        rowptr[i] = r;
        cursor[i] = r;
        dis[i] = rsqrtf((float)cnt[i]);
    }
    if (i == 0) rowptr[n] = EN;
}

__global__ void scatter_k(const int* __restrict__ esrc, const int* __restrict__ edst,
                          int* __restrict__ cursor, int* __restrict__ colidx, int E, int EN) {
    int i = blockIdx.x * 256 + threadIdx.x;
    if (i >= EN) return;
    int s, d;
    if (i < E) { s = esrc[i]; d = edst[i]; }
    else       { s = i - E; d = s; }
    int pos = atomicAdd(&cursor[d], 1);
    colidx[pos] = s;
}

// ---------------- all-weights transpose + fp16 convert (one launch) ----------------
// dst layout [M][K] fp16 from src [K][M] fp32.

__global__ void wtx_all_k(const float* __restrict__ gcn_in_w, const float* __restrict__ gcn_res_w,
                          const float* __restrict__ gat_in_w,
                          const float* __restrict__ gcn_w, const float* __restrict__ gat_w,
                          const float* __restrict__ gcn_c1w, const float* __restrict__ gat_c1w,
                          const float* __restrict__ gcn_c3w, const float* __restrict__ gat_c3w,
                          const float* __restrict__ fin_w,
                          __half* __restrict__ WTin, __half* __restrict__ WTg,
                          __half* __restrict__ WTa, __half* __restrict__ WTc1,
                          __half* __restrict__ WTc3, __half* __restrict__ WTfin) {
    int idx = blockIdx.x * 256 + threadIdx.x;
    const float* src;
    __half* dst;
    int K, M, o;
    if (idx < 24576) {                      // 3x (64x128) input mats
        int mi = idx >> 13; o = idx & 8191;
        src = mi == 0 ? gcn_in_w : (mi == 1 ? gcn_res_w : gat_in_w);
        dst = WTin + mi * 8192; K = 64; M = 128;
    } else if (idx < 73728) {               // 3x (128x128) gcn layer mats
        int r = idx - 24576; int mi = r >> 14; o = r & 16383;
        src = gcn_w + mi * 16384; dst = WTg + mi * 16384; K = 128; M = 128;
    } else if (idx < 122880) {              // 3x (128x128) gat layer mats
        int r = idx - 73728; int mi = r >> 14; o = r & 16383;
        src = gat_w + mi * 16384; dst = WTa + mi * 16384; K = 128; M = 128;
    } else if (idx < 139264) {              // 2x (128x64) c1 mats
        int r = idx - 122880; int mi = r >> 13; o = r & 8191;
        src = mi ? gat_c1w : gcn_c1w; dst = WTc1 + mi * 8192; K = 128; M = 64;
    } else if (idx < 147456) {              // 2x (32x128) c3 mats
        int r = idx - 139264; int mi = r >> 12; o = r & 4095;
        src = mi ? gat_c3w : gcn_c3w; dst = WTc3 + mi * 4096; K = 32; M = 128;
    } else if (idx < 155648) {              // fin (128x64)
        o = idx - 147456; src = fin_w; dst = WTfin; K = 128; M = 64;
    } else return;
    int mcol = o / K, k = o - mcol * K;
    dst[o] = (__half)src[k * M + mcol];
}

// ---------------- fp32 GEMM helper (only the tiny 64->32 tail keeps it) ----------------

#define FMA4R(A_, xv, w0, w1, w2, w3)                                  \
    A_.x += xv.x * w0.x + xv.y * w1.x + xv.z * w2.x + xv.w * w3.x;     \
    A_.y += xv.x * w0.y + xv.y * w1.y + xv.z * w2.y + xv.w * w3.y;     \
    A_.z += xv.x * w0.z + xv.y * w1.z + xv.z * w2.z + xv.w * w3.z;     \
    A_.w += xv.x * w0.w + xv.y * w1.w + xv.z * w2.w + xv.w * w3.w;

template <int K, int M>
__device__ __forceinline__ void gemm4(const float* __restrict__ Ws,
                                      const float* xa, const float* xb,
                                      const float* xc, const float* xd, int c,
                                      float4& A, float4& B, float4& C, float4& D) {
#pragma unroll 4
    for (int k = 0; k < K; k += 4) {
        float4 va = ld4(xa + k), vb = ld4(xb + k), vc = ld4(xc + k), vd = ld4(xd + k);
        const float* wp = Ws + k * M + c;
        float4 w0 = ld4(wp), w1 = ld4(wp + M), w2 = ld4(wp + 2 * M), w3 = ld4(wp + 3 * M);
        FMA4R(A, va, w0, w1, w2, w3)
        FMA4R(B, vb, w0, w1, w2, w3)
        FMA4R(C, vc, w0, w1, w2, w3)
        FMA4R(D, vd, w0, w1, w2, w3)
    }
}

template <int K, int M>
__global__ __launch_bounds__(256)
void tail2_k(const float* __restrict__ X0, const float* __restrict__ W0, const float* __restrict__ b0,
             float* __restrict__ Y0,
             const float* __restrict__ X1, const float* __restrict__ W1, const float* __restrict__ b1,
             float* __restrict__ Y1,
             int n, int gper, int do_relu) {
    constexpr int CG = M / 4, RPB = 256 / CG;
    bool s1 = blockIdx.x >= gper;
    int blk = s1 ? blockIdx.x - gper : blockIdx.x;
    const float* X = s1 ? X1 : X0;
    const float* W = s1 ? W1 : W0;
    const float* bi = s1 ? b1 : b0;
    float* Y = s1 ? Y1 : Y0;
    __shared__ float Ws[K * M];
    for (int i = threadIdx.x; i < K * M; i += 256) Ws[i] = W[i];
    __syncthreads();
    int cg = threadIdx.x % CG, r = threadIdx.x / CG, c = cg * 4;
    int ra = blk * (4 * RPB) + r, rb = ra + RPB, rc = ra + 2 * RPB, rd = ra + 3 * RPB;
    const float* xa = X + (size_t)(ra < n ? ra : 0) * K;
    const float* xb = X + (size_t)(rb < n ? rb : 0) * K;
    const float* xc = X + (size_t)(rc < n ? rc : 0) * K;
    const float* xd = X + (size_t)(rd < n ? rd : 0) * K;
    float4 A = f4z(), B = f4z(), C = f4z(), D = f4z();
    gemm4<K, M>(Ws, xa, xb, xc, xd, c, A, B, C, D);
    float4 bv = ld4(bi + c);
    A = f4bias(A, bv); B = f4bias(B, bv); C = f4bias(C, bv); D = f4bias(D, bv);
    if (do_relu) { A = f4relu(A); B = f4relu(B); C = f4relu(C); D = f4relu(D); }
    if (ra < n) st4(Y + (size_t)ra * M + c, A);
    if (rb < n) st4(Y + (size_t)rb * M + c, B);
    if (rc < n) st4(Y + (size_t)rc * M + c, C);
    if (rd < n) st4(Y + (size_t)rd * M + c, D);
}

// ---------------- MFMA dense kernels ----------------

__device__ __forceinline__ f16x8 mk_af(const float* xr, int kb) {
    float4 v0 = ld4(xr + kb), v1 = ld4(xr + kb + 4);
    f16x8 af;
    af[0] = (_Float16)v0.x; af[1] = (_Float16)v0.y;
    af[2] = (_Float16)v0.z; af[3] = (_Float16)v0.w;
    af[4] = (_Float16)v1.x; af[5] = (_Float16)v1.y;
    af[6] = (_Float16)v1.z; af[7] = (_Float16)v1.w;
    return af;
}

// input stage: 3 weight sets, same X (K=64, M=128), bias only, fp32 out
__global__ __launch_bounds__(256)
void mfma_lin3_k(const float* __restrict__ X, const __half* __restrict__ WTin,
                 const float* __restrict__ b0, float* __restrict__ Y0,
                 const float* __restrict__ b1, float* __restrict__ Y1,
                 const float* __restrict__ b2, float* __restrict__ Y2,
                 int n, int gper) {
    constexpr int K = 64, CT = 8;
    int set = blockIdx.x / gper, blk = blockIdx.x % gper;
    const __half* WT = WTin + (size_t)set * 8192;
    const float* bi = set == 0 ? b0 : (set == 1 ? b1 : b2);
    float* Y = set == 0 ? Y0 : (set == 1 ? Y1 : Y2);
    int wave = threadIdx.x >> 6, lane = threadIdx.x & 63;
    int m = lane & 15, quad = lane >> 4;
    int row0 = blk * 64 + wave * 16;
    int arow = min(row0 + m, n - 1);
    const float* xr = X + (size_t)arow * K;
    f32x4 acc[CT];
#pragma unroll
    for (int ct = 0; ct < CT; ++ct) acc[ct] = (f32x4){0.f, 0.f, 0.f, 0.f};
#pragma unroll
    for (int k32 = 0; k32 < K / 32; ++k32) {
        int kb = k32 * 32 + quad * 8;
        f16x8 af = mk_af(xr, kb);
#pragma unroll
        for (int ct = 0; ct < CT; ++ct) {
            f16x8 bf = *reinterpret_cast<const f16x8*>(WT + (size_t)(ct * 16 + m) * K + kb);
            acc[ct] = __builtin_amdgcn_mfma_f32_16x16x32_f16(af, bf, acc[ct], 0, 0, 0);
        }
    }
#pragma unroll
    for (int ct = 0; ct < CT; ++ct) {
        int col = ct * 16 + m;
        float cb = bi[col];
#pragma unroll
        for (int reg = 0; reg < 4; ++reg) {
            int row = row0 + quad * 4 + reg;
            if (row < n) Y[(size_t)row * 128 + col] = acc[ct][reg] + cb;
        }
    }
}

// tail pair: two (X, WT, b[,bn]) sets, fp32 out
template <int K, int M>
__global__ __launch_bounds__(256)
void mfma_lin2_k(const float* __restrict__ X0, const __half* __restrict__ WT0,
                 const float* __restrict__ b0, const float* __restrict__ g0,
                 const float* __restrict__ bb0, float* __restrict__ Y0,
                 const float* __restrict__ X1, const __half* __restrict__ WT1,
                 const float* __restrict__ b1, const float* __restrict__ g1,
                 const float* __restrict__ bb1, float* __restrict__ Y1,
                 int n, int gper, int do_relu) {
    constexpr int CT = M / 16;
    bool s1 = blockIdx.x >= gper;
    int blk = s1 ? blockIdx.x - gper : blockIdx.x;
    const float* X = s1 ? X1 : X0;
    const __half* WT = s1 ? WT1 : WT0;
    const float* bi = s1 ? b1 : b0;
    const float* bg = s1 ? g1 : g0;
    const float* bb = s1 ? bb1 : bb0;
    float* Y = s1 ? Y1 : Y0;
    int wave = threadIdx.x >> 6, lane = threadIdx.x & 63;
    int m = lane & 15, quad = lane >> 4;
    int row0 = blk * 64 + wave * 16;
    int arow = min(row0 + m, n - 1);
    const float* xr = X + (size_t)arow * K;
    f32x4 acc[CT];
#pragma unroll
    for (int ct = 0; ct < CT; ++ct) acc[ct] = (f32x4){0.f, 0.f, 0.f, 0.f};
#pragma unroll
    for (int k32 = 0; k32 < K / 32; ++k32) {
        int kb = k32 * 32 + quad * 8;
        f16x8 af = mk_af(xr, kb);
#pragma unroll
        for (int ct = 0; ct < CT; ++ct) {
            f16x8 bf = *reinterpret_cast<const f16x8*>(WT + (size_t)(ct * 16 + m) * K + kb);
            acc[ct] = __builtin_amdgcn_mfma_f32_16x16x32_f16(af, bf, acc[ct], 0, 0, 0);
        }
    }
#pragma unroll
    for (int ct = 0; ct < CT; ++ct) {
        int col = ct * 16 + m;
        float cb = bi[col];
        float cg = bg ? bg[col] * RSQ_BN : 1.f;
        float cbb = bg ? bb[col] : 0.f;
#pragma unroll
        for (int reg = 0; reg < 4; ++reg) {
            int row = row0 + quad * 4 + reg;
            if (row < n) {
                float v = acc[ct][reg] + cb;
                if (do_relu) v = fmaxf(v, 0.f);
                if (bg) v = v * cg + cbb;
                Y[(size_t)row * M + col] = v;
            }
        }
    }
}

// final: blend(0.6*XA+0.4*XB) @ fin(K=128,M=64) -> relu -> bn -> @fin2 -> out[n,2]
__global__ __launch_bounds__(256)
void mfma_linF_k(const float* __restrict__ XA, const float* __restrict__ XB,
                 const __half* __restrict__ WT, const float* __restrict__ bi,
                 const float* __restrict__ bg, const float* __restrict__ bb,
                 const float* __restrict__ w2, const float* __restrict__ b2,
                 float* __restrict__ out, int n) {
    constexpr int K = 128, M = 64, CT = 4;
    int wave = threadIdx.x >> 6, lane = threadIdx.x & 63;
    int m = lane & 15, quad = lane >> 4;
    int row0 = blockIdx.x * 64 + wave * 16;
    int arow = min(row0 + m, n - 1);
    const float* xra = XA + (size_t)arow * K;
    const float* xrb = XB + (size_t)arow * K;
    f32x4 acc[CT];
#pragma unroll
    for (int ct = 0; ct < CT; ++ct) acc[ct] = (f32x4){0.f, 0.f, 0.f, 0.f};
#pragma unroll
    for (int k32 = 0; k32 < K / 32; ++k32) {
        int kb = k32 * 32 + quad * 8;
        float4 a0 = ld4(xra + kb), a1 = ld4(xra + kb + 4);
        float4 u0 = ld4(xrb + kb), u1 = ld4(xrb + kb + 4);
        f16x8 af;
        af[0] = (_Float16)(0.6f * a0.x + 0.4f * u0.x);
        af[1] = (_Float16)(0.6f * a0.y + 0.4f * u0.y);
        af[2] = (_Float16)(0.6f * a0.z + 0.4f * u0.z);
        af[3] = (_Float16)(0.6f * a0.w + 0.4f * u0.w);
        af[4] = (_Float16)(0.6f * a1.x + 0.4f * u1.x);
        af[5] = (_Float16)(0.6f * a1.y + 0.4f * u1.y);
        af[6] = (_Float16)(0.6f * a1.z + 0.4f * u1.z);
        af[7] = (_Float16)(0.6f * a1.w + 0.4f * u1.w);
#pragma unroll
        for (int ct = 0; ct < CT; ++ct) {
            f16x8 bf = *reinterpret_cast<const f16x8*>(WT + (size_t)(ct * 16 + m) * K + kb);
            acc[ct] = __builtin_amdgcn_mfma_f32_16x16x32_f16(af, bf, acc[ct], 0, 0, 0);
        }
    }
    float p0[4] = {0.f, 0.f, 0.f, 0.f}, p1[4] = {0.f, 0.f, 0.f, 0.f};
#pragma unroll
    for (int ct = 0; ct < CT; ++ct) {
        int col = ct * 16 + m;
        float cb = bi[col];
        float cg = bg[col] * RSQ_BN;
        float cbb = bb[col];
        float w20 = w2[2 * col], w21 = w2[2 * col + 1];
#pragma unroll
        for (int reg = 0; reg < 4; ++reg) {
            float v = fmaxf(acc[ct][reg] + cb, 0.f) * cg + cbb;
            p0[reg] += v * w20;
            p1[reg] += v * w21;
        }
    }
    for (int off = 1; off < 16; off <<= 1) {
#pragma unroll
        for (int reg = 0; reg < 4; ++reg) {
            p0[reg] += __shfl_xor(p0[reg], off);
            p1[reg] += __shfl_xor(p1[reg], off);
        }
    }
    if (m == 0) {
#pragma unroll
        for (int reg = 0; reg < 4; ++reg) {
            int row = row0 + quad * 4 + reg;
            if (row < n) {
                out[row * 2] = p0[reg] + b2[0];
                out[row * 2 + 1] = p1[reg] + b2[1];
            }
        }
    }
}

// ---------------- per-layer pair GEMM via MFMA (gcn dis-fold + gat attn dots) ----------------

__global__ __launch_bounds__(256)
void dual128_mfma_k(const float* __restrict__ Xg, const __half* __restrict__ WTg,
                    __half* __restrict__ Yg,
                    const float* __restrict__ Xa, const __half* __restrict__ WTa,
                    __half* __restrict__ Ya,
                    const float* __restrict__ dis,
                    const float* __restrict__ asrc, const float* __restrict__ adst,
                    float* __restrict__ avp, float* __restrict__ bvp,
                    int hh, int n, int gper) {
    bool gat = blockIdx.x >= gper;
    int blk = gat ? blockIdx.x - gper : blockIdx.x;
    const float* X = gat ? Xa : Xg;
    const __half* WT = gat ? WTa : WTg;
    __half* Y = gat ? Ya : Yg;
    int wave = threadIdx.x >> 6;
    int lane = threadIdx.x & 63;
    int m = lane & 15, quad = lane >> 4;
    int row0 = blk * 64 + wave * 16;
    int arow = min(row0 + m, n - 1);
    const float* xr = X + (size_t)arow * 128;
    f32x4 acc[8];
#pragma unroll
    for (int ct = 0; ct < 8; ++ct) acc[ct] = (f32x4){0.f, 0.f, 0.f, 0.f};
#pragma unroll
    for (int k32 = 0; k32 < 4; ++k32) {
        int kb = k32 * 32 + quad * 8;
        f16x8 af = mk_af(xr, kb);
#pragma unroll
        for (int ct = 0; ct < 8; ++ct) {
            f16x8 bf = *reinterpret_cast<const f16x8*>(WT + (size_t)(ct * 16 + m) * 128 + kb);
            acc[ct] = __builtin_amdgcn_mfma_f32_16x16x32_f16(af, bf, acc[ct], 0, 0, 0);
        }
    }
    if (!gat) {
#pragma unroll
        for (int reg = 0; reg < 4; ++reg) {
            int row = row0 + quad * 4 + reg;
            if (row < n) {
                float dv = dis[row];
#pragma unroll
                for (int ct = 0; ct < 8; ++ct)
                    Y[(size_t)row * 128 + ct * 16 + m] = (__half)(acc[ct][reg] * dv);
            }
        }
    } else {
        float cas[8], cad[8];
#pragma unroll
        for (int ct = 0; ct < 8; ++ct) {
            cas[ct] = asrc[ct * 16 + m];
            cad[ct] = adst[ct * 16 + m];
        }
        int ctph = 8 / hh;   // col-tiles per head
#pragma unroll
        for (int reg = 0; reg < 4; ++reg) {
            int row = row0 + quad * 4 + reg;
            bool valid = row < n;
            if (valid) {
#pragma unroll
                for (int ct = 0; ct < 8; ++ct)
                    Y[(size_t)row * 128 + ct * 16 + m] = (__half)acc[ct][reg];
            }
            for (int h = 0; h < hh; ++h) {
                float sa = 0.f, sd = 0.f;
                for (int j = 0; j < ctph; ++j) {
                    int ct = h * ctph + j;
                    sa += acc[ct][reg] * cas[ct];
                    sd += acc[ct][reg] * cad[ct];
                }
                for (int off = 1; off < 16; off <<= 1) {
                    sa += __shfl_xor(sa, off);
                    sd += __shfl_xor(sd, off);
                }
                if (m == 0 && valid) {
                    avp[row * hh + h] = sa;
                    bvp[row * hh + h] = sd;
                }
            }
        }
    }
}

// ---------------- fused sparse aggregation: one row-walk, BOTH tables, 8-edge groups ----------------
// 16 lanes/node, 8 cols (16B fp16) per lane per table (full 128-col rows, coalesced).

__global__ __launch_bounds__(256)
void fused_gather_k(const int* __restrict__ rowptr, const int* __restrict__ colidx,
                    const float* __restrict__ dis,
                    const __half* __restrict__ Tg, const float* __restrict__ gbias,
                    const float* __restrict__ gbng, const float* __restrict__ gbnb,
                    const float* __restrict__ res, float* __restrict__ Yg,
                    const __half* __restrict__ Ta, const float* __restrict__ avp,
                    const float* __restrict__ bvp, const float* __restrict__ abias,
                    const float* __restrict__ abng, const float* __restrict__ abnb,
                    const float* __restrict__ fimp, float* __restrict__ Ya,
                    int n, int hh, int log2C) {
    int idx = blockIdx.x * 256 + threadIdx.x;
    int i = idx >> 4;
    if (i >= n) return;
    int c = (idx & 15) * 8;
    int h = c >> log2C;
    float ad = bvp[i * hh + h];
    int p0 = rowptr[i], p1 = rowptr[i + 1];
    float4 glo = f4z(), ghi = f4z();           // gcn accumulators (plain sum)
    float4 alo = f4z(), ahi = f4z();           // gat accumulators (online softmax)
    float m = -3.0e38f, s = 0.f;

#define GACC(qq)                                                                \
    {                                                                           \
        float4 t0 = h4f(make_uint2(qq.x, qq.y)), t1 = h4f(make_uint2(qq.z, qq.w)); \
        glo.x += t0.x; glo.y += t0.y; glo.z += t0.z; glo.w += t0.w;             \
        ghi.x += t1.x; ghi.y += t1.y; ghi.z += t1.z; ghi.w += t1.w;             \
    }
#define AACC(qq, ww)                                                            \
    {                                                                           \
        float4 t0 = h4f(make_uint2(qq.x, qq.y)), t1 = h4f(make_uint2(qq.z, qq.w)); \
        alo.x += t0.x * ww; alo.y += t0.y * ww; alo.z += t0.z * ww; alo.w += t0.w * ww; \
        ahi.x += t1.x * ww; ahi.y += t1.y * ww; ahi.z += t1.z * ww; ahi.w += t1.w * ww; \
    }

    int p = p0;
    for (; p + 8 <= p1; p += 8) {
        int sx[8]; float e[8]; uint4 qg[8], qa[8];
#pragma unroll
        for (int j = 0; j < 8; ++j) sx[j] = colidx[p + j];
#pragma unroll
        for (int j = 0; j < 8; ++j) e[j] = leaky02(avp[sx[j] * hh + h] + ad);
#pragma unroll
        for (int j = 0; j < 8; ++j)
            qg[j] = *reinterpret_cast<const uint4*>(Tg + (size_t)sx[j] * 128 + c);
#pragma unroll
        for (int j = 0; j < 8; ++j)
            qa[j] = *reinterpret_cast<const uint4*>(Ta + (size_t)sx[j] * 128 + c);
#pragma unroll
        for (int j = 0; j < 8; ++j) GACC(qg[j])
        float mc = fmaxf(fmaxf(fmaxf(e[0], e[1]), fmaxf(e[2], e[3])),
                         fmaxf(fmaxf(e[4], e[5]), fmaxf(e[6], e[7])));
        float mn = fmaxf(m, mc);
        float scale = expf(m - mn);
        alo = f4s(alo, scale);
        ahi = f4s(ahi, scale);
        float wsum = 0.f;
#pragma unroll
        for (int j = 0; j < 8; ++j) {
            float wj = expf(e[j] - mn);
            wsum += wj;
            AACC(qa[j], wj)
        }
        s = s * scale + wsum;
        m = mn;
    }
    for (; p < p1; ++p) {
        int s0 = colidx[p];
        float e0 = leaky02(avp[s0 * hh + h] + ad);
        uint4 qg0 = *reinterpret_cast<const uint4*>(Tg + (size_t)s0 * 128 + c);
        uint4 qa0 = *reinterpret_cast<const uint4*>(Ta + (size_t)s0 * 128 + c);
        GACC(qg0)
        float mn = fmaxf(m, e0);
        float scale = expf(m - mn);
        float w0 = expf(e0 - mn);
        s = s * scale + w0;
        alo = f4s(alo, scale);
        ahi = f4s(ahi, scale);
        AACC(qa0, w0)
        m = mn;
    }

    // ---- GCN epilogue ----
    {
        float di = dis[i];
        float4 b0 = ld4(gbias + c), b1 = ld4(gbias + c + 4);
        glo = make_float4(glo.x * di + b0.x, glo.y * di + b0.y, glo.z * di + b0.z, glo.w * di + b0.w);
        ghi = make_float4(ghi.x * di + b1.x, ghi.y * di + b1.y, ghi.z * di + b1.z, ghi.w * di + b1.w);
        float4 g0 = ld4(gbng + c), g1 = ld4(gbng + c + 4);
        g0 = f4s(g0, RSQ_BN); g1 = f4s(g1, RSQ_BN);
        float4 h0 = ld4(gbnb + c), h1 = ld4(gbnb + c + 4);
        glo = f4relu(f4bn(glo, g0, h0));
        ghi = f4relu(f4bn(ghi, g1, h1));
        if (res) {
            float4 r0 = ld4(res + (size_t)i * 128 + c), r1 = ld4(res + (size_t)i * 128 + c + 4);
            glo = f4bias(glo, r0); ghi = f4bias(ghi, r1);
        }
        st4(Yg + (size_t)i * 128 + c, glo);
        st4(Yg + (size_t)i * 128 + c + 4, ghi);
    }
    // ---- GAT epilogue ----
    {
        float si = 1.f / (s + 1e-16f);
        float4 b0 = ld4(abias + c), b1 = ld4(abias + c + 4);
        alo = make_float4(alo.x * si + b0.x, alo.y * si + b0.y, alo.z * si + b0.z, alo.w * si + b0.w);
        ahi = make_float4(ahi.x * si + b1.x, ahi.y * si + b1.y, ahi.z * si + b1.z, ahi.w * si + b1.w);
        float4 g0 = ld4(abng + c), g1 = ld4(abng + c + 4);
        g0 = f4s(g0, RSQ_BN); g1 = f4s(g1, RSQ_BN);
        float4 h0 = ld4(abnb + c), h1 = ld4(abnb + c + 4);
        alo = f4bn(alo, g0, h0);
        ahi = f4bn(ahi, g1, h1);
        alo.x = alo.x > 0.f ? alo.x : expm1f(alo.x);
        alo.y = alo.y > 0.f ? alo.y : expm1f(alo.y);
        alo.z = alo.z > 0.f ? alo.z : expm1f(alo.z);
        alo.w = alo.w > 0.f ? alo.w : expm1f(alo.w);
        ahi.x = ahi.x > 0.f ? ahi.x : expm1f(ahi.x);
        ahi.y = ahi.y > 0.f ? ahi.y : expm1f(ahi.y);
        ahi.z = ahi.z > 0.f ? ahi.z : expm1f(ahi.z);
        ahi.w = ahi.w > 0.f ? ahi.w : expm1f(ahi.w);
        if (fimp) {
            float4 f0 = ld4(fimp + c), f1 = ld4(fimp + c + 4);
            alo = make_float4(alo.x * f0.x, alo.y * f0.y, alo.z * f0.z, alo.w * f0.w);
            ahi = make_float4(ahi.x * f1.x, ahi.y * f1.y, ahi.z * f1.z, ahi.w * f1.w);
        }
        st4(Ya + (size_t)i * 128 + c, alo);
        st4(Ya + (size_t)i * 128 + c + 4, ahi);
    }
#undef GACC
#undef AACC
}

// ---------------- host orchestration ----------------

static inline int cdiv(int a, int b) { return (a + b - 1) / b; }

extern "C" void kernel_launch(void* const* d_in, const int* in_sizes, int n_in,
                              void* d_out, int out_size, void* d_ws, size_t ws_size,
                              hipStream_t stream) {
    const float* x       = (const float*)d_in[0];
    const int*   ei      = (const int*)d_in[1];
    const float* gcn_in_w = (const float*)d_in[2];
    const float* gcn_in_b = (const float*)d_in[3];
    const float* gcn_res_w = (const float*)d_in[4];
    const float* gcn_res_b = (const float*)d_in[5];
    const float* gcn_w   = (const float*)d_in[6];
    const float* gcn_b   = (const float*)d_in[7];
    const float* gcn_bn_g = (const float*)d_in[8];
    const float* gcn_bn_b = (const float*)d_in[9];
    const float* gcn_c1w = (const float*)d_in[10];
    const float* gcn_c1b = (const float*)d_in[11];
    const float* gcn_c2w = (const float*)d_in[12];
    const float* gcn_c2b = (const float*)d_in[13];
    const float* gcn_c3w = (const float*)d_in[14];
    const float* gcn_c3b = (const float*)d_in[15];
    const float* gat_in_w = (const float*)d_in[16];
    const float* gat_in_b = (const float*)d_in[17];
    const float* gat_w   = (const float*)d_in[18];
    const float* gat_asrc = (const float*)d_in[19];
    const float* gat_adst = (const float*)d_in[20];
    const float* gat_b   = (const float*)d_in[21];
    const float* gat_bn_g = (const float*)d_in[22];
    const float* gat_bn_b = (const float*)d_in[23];
    const float* feat_imp = (const float*)d_in[24];
    const float* gat_c1w = (const float*)d_in[25];
    const float* gat_c1b = (const float*)d_in[26];
    const float* gat_cbn_g = (const float*)d_in[27];
    const float* gat_cbn_b = (const float*)d_in[28];
    const float* gat_c2w = (const float*)d_in[29];
    const float* gat_c2b = (const float*)d_in[30];
    const float* gat_c3w = (const float*)d_in[31];
    const float* gat_c3b = (const float*)d_in[32];
    const float* fin_w   = (const float*)d_in[33];
    const float* fin_b   = (const float*)d_in[34];
    const float* fin_bn_g = (const float*)d_in[35];
    const float* fin_bn_b = (const float*)d_in[36];
    const float* fin2_w  = (const float*)d_in[37];
    const float* fin2_b  = (const float*)d_in[38];

    const int N = in_sizes[0] / 64;
    const int E = in_sizes[1] / 2;
    const int EN = E + N;
    const int* esrc = ei;
    const int* edst = ei + E;

    // workspace carve (256B aligned)
    char* wp = (char*)d_ws;
    auto alloc = [&](size_t bytes) -> void* {
        void* p = (void*)wp;
        wp += (bytes + 255) & ~(size_t)255;
        return p;
    };
    int* cnt    = (int*)alloc((size_t)N * 4);
    int* rowptr = (int*)alloc((size_t)(N + 1) * 4);
    int* cursor = (int*)alloc((size_t)N * 4);
    int* bsum   = (int*)alloc((size_t)256 * 4);
    int* colidx = (int*)alloc((size_t)EN * 4);
    float* dis  = (float*)alloc((size_t)N * 4);
    float* A    = (float*)alloc((size_t)N * 128 * 4);   // gcn ping / GOUT reuse
    float* B    = (float*)alloc((size_t)N * 128 * 4);   // gcn pong
    float* G    = (float*)alloc((size_t)N * 128 * 4);   // gat ping / AOUT reuse
    float* H    = (float*)alloc((size_t)N * 128 * 4);   // gat pong
    float* R    = (float*)alloc((size_t)N * 128 * 4);   // gcn residual
    __half* Th1 = (__half*)alloc((size_t)N * 128 * 2);  // aliased as h1g after layers
    __half* Th2 = (__half*)alloc((size_t)N * 128 * 2);  // aliased as h1a after layers
    float* h2g  = (float*)alloc((size_t)N * 32 * 4);
    float* h2a  = (float*)alloc((size_t)N * 32 * 4);
    float* avv  = (float*)alloc((size_t)N * 4 * 4);
    float* bvv  = (float*)alloc((size_t)N * 4 * 4);
    __half* WTin = (__half*)alloc((size_t)3 * 8192 * 2);
    __half* WTg  = (__half*)alloc((size_t)3 * 16384 * 2);
    __half* WTa  = (__half*)alloc((size_t)3 * 16384 * 2);
    __half* WTc1 = (__half*)alloc((size_t)2 * 8192 * 2);
    __half* WTc3 = (__half*)alloc((size_t)2 * 4096 * 2);
    __half* WTfin = (__half*)alloc((size_t)8192 * 2);
    float* h1g = (float*)Th1;   // N*64*4 == N*128*2 bytes
    float* h1a = (float*)Th2;

    // ---- CSR build + all-weight transpose ----
    const int nScanB = cdiv(N, 256);
    zero_i32_k<<<cdiv(N, 256), 256, 0, stream>>>(cnt, N);
    hist_k<<<cdiv(EN, 256), 256, 0, stream>>>(edst, cnt, E, EN);
    scanA_k<<<nScanB, 256, 0, stream>>>(cnt, rowptr, bsum, N);
    scanB_k<<<1, 256, 0, stream>>>(bsum, nScanB);
    scanC_k<<<nScanB, 256, 0, stream>>>(cnt, bsum, rowptr, cursor, dis, N, EN);
    scatter_k<<<cdiv(EN, 256), 256, 0, stream>>>(esrc, edst, cursor, colidx, E, EN);
    wtx_all_k<<<608, 256, 0, stream>>>(gcn_in_w, gcn_res_w, gat_in_w, gcn_w, gat_w,
                                       gcn_c1w, gat_c1w, gcn_c3w, gat_c3w, fin_w,
                                       WTin, WTg, WTa, WTc1, WTc3, WTfin);

    const int g64r  = cdiv(N, 64);    // mfma kernels: 64 rows/block
    const int g128r = cdiv(N, 128);   // fp32 tail M=32
    const int gG    = cdiv(N, 16);    // gather: 16 nodes/block

    // ---- input stage: gcn_in -> A, gcn_res -> R, gat_in -> G ----
    mfma_lin3_k<<<3 * g64r, 256, 0, stream>>>(x, WTin, gcn_in_b, A, gcn_res_b, R,
                                              gat_in_b, G, N, g64r);

    // ---- 3 layers, both branches in lockstep ----
    const int heads_arr[3] = {4, 4, 1};
    float* gcur = A; float* gnxt = B;
    float* acur = G; float* anxt = H;
    for (int i = 0; i < 3; ++i) {
        int hh = heads_arr[i];
        int log2C = (hh == 4) ? 5 : 7;
        dual128_mfma_k<<<2 * g64r, 256, 0, stream>>>(gcur, WTg + (size_t)i * 16384, Th1,
                                                     acur, WTa + (size_t)i * 16384, Th2, dis,
                                                     gat_asrc + i * 128, gat_adst + i * 128,
                                                     avv, bvv, hh, N, g64r);
        fused_gather_k<<<gG, 256, 0, stream>>>(rowptr, colidx, dis,
                                               Th1, gcn_b + i * 128, gcn_bn_g + i * 128,
                                               gcn_bn_b + i * 128, (i == 1) ? R : nullptr, gnxt,
                                               Th2, avv, bvv, gat_b + i * 128,
                                               gat_bn_g + i * 128, gat_bn_b + i * 128,
                                               (i == 2) ? feat_imp : nullptr, anxt,
                                               N, hh, log2C);
        float* t = gcur; gcur = gnxt; gnxt = t;
        t = acur; acur = anxt; anxt = t;
    }
    // gcur = gcn final xp (B), acur = gat final xg (H)

    // ---- MLP tails ----  (h1g/h1a alias Th1/Th2 — Th no longer needed)
    mfma_lin2_k<128, 64><<<2 * g64r, 256, 0, stream>>>(
        gcur, WTc1, gcn_c1b, nullptr, nullptr, h1g,
        acur, WTc1 + 8192, gat_c1b, gat_cbn_g, gat_cbn_b, h1a, N, g64r, 1);
    tail2_k<64, 32><<<2 * g128r, 256, 0, stream>>>(
        h1g, gcn_c2w, gcn_c2b, h2g,
        h1a, gat_c2w, gat_c2b, h2a, N, g128r, 1);
    mfma_lin2_k<32, 128><<<2 * g64r, 256, 0, stream>>>(
        h2g, WTc3, gcn_c3b, nullptr, nullptr, A,
        h2a, WTc3 + 4096, gat_c3b, nullptr, nullptr, G, N, g64r, 0);

    // ---- fusion tail: blend + fin linear + bn + classifier ----
    mfma_linF_k<<<g64r, 256, 0, stream>>>(A, G, WTfin, fin_b, fin_bn_g, fin_bn_b,
                                          fin2_w, fin2_b, (float*)d_out, N);
}

// Round 14
// 508.436 us; speedup vs baseline: 1.1386x; 1.1192x over previous
//
#include <hip/hip_runtime.h>
#include <hip/hip_fp16.h>

// BN scale constant: 1/sqrt(1+1e-5)
#define RSQ_BN 0.9999950000374997f

typedef _Float16 f16x8 __attribute__((ext_vector_type(8)));
typedef float f32x4 __attribute__((ext_vector_type(4)));

__device__ __forceinline__ float leaky02(float x) { return x > 0.f ? x : 0.2f * x; }

__device__ __forceinline__ float4 ld4(const float* p) {
    return *reinterpret_cast<const float4*>(p);
}
__device__ __forceinline__ void st4(float* p, float4 v) {
    *reinterpret_cast<float4*>(p) = v;
}
__device__ __forceinline__ float4 h4f(uint2 u) {
    union { uint2 u; __half2 h[2]; } pk;
    pk.u = u;
    float2 lo = __half22float2(pk.h[0]);
    float2 hi = __half22float2(pk.h[1]);
    return make_float4(lo.x, lo.y, hi.x, hi.y);
}
__device__ __forceinline__ float4 f4z() { return make_float4(0.f, 0.f, 0.f, 0.f); }
__device__ __forceinline__ float4 f4bias(float4 v, float4 b) {
    return make_float4(v.x + b.x, v.y + b.y, v.z + b.z, v.w + b.w);
}
__device__ __forceinline__ float4 f4relu(float4 v) {
    return make_float4(fmaxf(v.x, 0.f), fmaxf(v.y, 0.f), fmaxf(v.z, 0.f), fmaxf(v.w, 0.f));
}
__device__ __forceinline__ float4 f4bn(float4 v, float4 g, float4 b) {
    return make_float4(v.x * g.x + b.x, v.y * g.y + b.y, v.z * g.z + b.z, v.w * g.w + b.w);
}
__device__ __forceinline__ float4 f4s(float4 v, float s) {
    return make_float4(v.x * s, v.y * s, v.z * s, v.w * s);
}

// ---------------- CSR build ----------------

__global__ void zero_i32_k(int* __restrict__ p, int n) {
    int i = blockIdx.x * 256 + threadIdx.x;
    if (i < n) p[i] = 0;
}

__global__ void hist_k(const int* __restrict__ edst, int* __restrict__ cnt, int E, int EN) {
    int i = blockIdx.x * 256 + threadIdx.x;
    if (i >= EN) return;
    int d = (i < E) ? edst[i] : (i - E);   // self-loop for i>=E
    atomicAdd(&cnt[d], 1);
}

__global__ __launch_bounds__(256)
void scanA_k(const int* __restrict__ cnt, int* __restrict__ rowptr,
             int* __restrict__ bsum, int n) {
    __shared__ int sh[256];
    int t = threadIdx.x;
    int i = blockIdx.x * 256 + t;
    int v = (i < n) ? cnt[i] : 0;
    sh[t] = v;
    __syncthreads();
#pragma unroll
    for (int off = 1; off < 256; off <<= 1) {
        int u = 0;
        if (t >= off) u = sh[t - off];
        __syncthreads();
        sh[t] += u;
        __syncthreads();
    }
    if (i < n) rowptr[i] = sh[t] - v;
    if (t == 255) bsum[blockIdx.x] = sh[255];
}

__global__ __launch_bounds__(256)
void scanB_k(int* __restrict__ bsum, int nb) {
    __shared__ int sh[256];
    int t = threadIdx.x;
    int v = (t < nb) ? bsum[t] : 0;
    sh[t] = v;
    __syncthreads();
#pragma unroll
    for (int off = 1; off < 256; off <<= 1) {
        int u = 0;
        if (t >= off) u = sh[t - off];
        __syncthreads();
        sh[t] += u;
        __syncthreads();
    }
    if (t < nb) bsum[t] = sh[t] - v;
}

__global__ __launch_bounds__(256)
void scanC_k(const int* __restrict__ cnt, const int* __restrict__ bsum,
             int* __restrict__ rowptr, int* __restrict__ cursor,
             float* __restrict__ dis, int n, int EN) {
    int i = blockIdx.x * 256 + threadIdx.x;
    if (i < n) {
        int r = rowptr[i] + bsum[blockIdx.x];
        rowptr[i] = r;
        cursor[i] = r;
        dis[i] = rsqrtf((float)cnt[i]);
    }
    if (i == 0) rowptr[n] = EN;
}

__global__ void scatter_k(const int* __restrict__ esrc, const int* __restrict__ edst,
                          int* __restrict__ cursor, int* __restrict__ colidx, int E, int EN) {
    int i = blockIdx.x * 256 + threadIdx.x;
    if (i >= EN) return;
    int s, d;
    if (i < E) { s = esrc[i]; d = edst[i]; }
    else       { s = i - E; d = s; }
    int pos = atomicAdd(&cursor[d], 1);
    colidx[pos] = s;
}

// ---------------- all-weights transpose + fp16 convert (one launch) ----------------
// dst layout [M][K] fp16 from src [K][M] fp32.

__global__ void wtx_all_k(const float* __restrict__ gcn_in_w, const float* __restrict__ gcn_res_w,
                          const float* __restrict__ gat_in_w,
                          const float* __restrict__ gcn_w, const float* __restrict__ gat_w,
                          const float* __restrict__ gcn_c1w, const float* __restrict__ gat_c1w,
                          const float* __restrict__ gcn_c3w, const float* __restrict__ gat_c3w,
                          const float* __restrict__ fin_w,
                          __half* __restrict__ WTin, __half* __restrict__ WTg,
                          __half* __restrict__ WTa, __half* __restrict__ WTc1,
                          __half* __restrict__ WTc3, __half* __restrict__ WTfin) {
    int idx = blockIdx.x * 256 + threadIdx.x;
    const float* src;
    __half* dst;
    int K, M, o;
    if (idx < 24576) {                      // 3x (64x128) input mats
        int mi = idx >> 13; o = idx & 8191;
        src = mi == 0 ? gcn_in_w : (mi == 1 ? gcn_res_w : gat_in_w);
        dst = WTin + mi * 8192; K = 64; M = 128;
    } else if (idx < 73728) {               // 3x (128x128) gcn layer mats
        int r = idx - 24576; int mi = r >> 14; o = r & 16383;
        src = gcn_w + mi * 16384; dst = WTg + mi * 16384; K = 128; M = 128;
    } else if (idx < 122880) {              // 3x (128x128) gat layer mats
        int r = idx - 73728; int mi = r >> 14; o = r & 16383;
        src = gat_w + mi * 16384; dst = WTa + mi * 16384; K = 128; M = 128;
    } else if (idx < 139264) {              // 2x (128x64) c1 mats
        int r = idx - 122880; int mi = r >> 13; o = r & 8191;
        src = mi ? gat_c1w : gcn_c1w; dst = WTc1 + mi * 8192; K = 128; M = 64;
    } else if (idx < 147456) {              // 2x (32x128) c3 mats
        int r = idx - 139264; int mi = r >> 12; o = r & 4095;
        src = mi ? gat_c3w : gcn_c3w; dst = WTc3 + mi * 4096; K = 32; M = 128;
    } else if (idx < 155648) {              // fin (128x64)
        o = idx - 147456; src = fin_w; dst = WTfin; K = 128; M = 64;
    } else return;
    int mcol = o / K, k = o - mcol * K;
    dst[o] = (__half)src[k * M + mcol];
}

// ---------------- fp32 GEMM helper (only the tiny 64->32 tail keeps it) ----------------

#define FMA4R(A_, xv, w0, w1, w2, w3)                                  \
    A_.x += xv.x * w0.x + xv.y * w1.x + xv.z * w2.x + xv.w * w3.x;     \
    A_.y += xv.x * w0.y + xv.y * w1.y + xv.z * w2.y + xv.w * w3.y;     \
    A_.z += xv.x * w0.z + xv.y * w1.z + xv.z * w2.z + xv.w * w3.z;     \
    A_.w += xv.x * w0.w + xv.y * w1.w + xv.z * w2.w + xv.w * w3.w;

template <int K, int M>
__device__ __forceinline__ void gemm4(const float* __restrict__ Ws,
                                      const float* xa, const float* xb,
                                      const float* xc, const float* xd, int c,
                                      float4& A, float4& B, float4& C, float4& D) {
#pragma unroll 4
    for (int k = 0; k < K; k += 4) {
        float4 va = ld4(xa + k), vb = ld4(xb + k), vc = ld4(xc + k), vd = ld4(xd + k);
        const float* wp = Ws + k * M + c;
        float4 w0 = ld4(wp), w1 = ld4(wp + M), w2 = ld4(wp + 2 * M), w3 = ld4(wp + 3 * M);
        FMA4R(A, va, w0, w1, w2, w3)
        FMA4R(B, vb, w0, w1, w2, w3)
        FMA4R(C, vc, w0, w1, w2, w3)
        FMA4R(D, vd, w0, w1, w2, w3)
    }
}

template <int K, int M>
__global__ __launch_bounds__(256)
void tail2_k(const float* __restrict__ X0, const float* __restrict__ W0, const float* __restrict__ b0,
             float* __restrict__ Y0,
             const float* __restrict__ X1, const float* __restrict__ W1, const float* __restrict__ b1,
             float* __restrict__ Y1,
             int n, int gper, int do_relu) {
    constexpr int CG = M / 4, RPB = 256 / CG;
    bool s1 = blockIdx.x >= gper;
    int blk = s1 ? blockIdx.x - gper : blockIdx.x;
    const float* X = s1 ? X1 : X0;
    const float* W = s1 ? W1 : W0;
    const float* bi = s1 ? b1 : b0;
    float* Y = s1 ? Y1 : Y0;
    __shared__ float Ws[K * M];
    for (int i = threadIdx.x; i < K * M; i += 256) Ws[i] = W[i];
    __syncthreads();
    int cg = threadIdx.x % CG, r = threadIdx.x / CG, c = cg * 4;
    int ra = blk * (4 * RPB) + r, rb = ra + RPB, rc = ra + 2 * RPB, rd = ra + 3 * RPB;
    const float* xa = X + (size_t)(ra < n ? ra : 0) * K;
    const float* xb = X + (size_t)(rb < n ? rb : 0) * K;
    const float* xc = X + (size_t)(rc < n ? rc : 0) * K;
    const float* xd = X + (size_t)(rd < n ? rd : 0) * K;
    float4 A = f4z(), B = f4z(), C = f4z(), D = f4z();
    gemm4<K, M>(Ws, xa, xb, xc, xd, c, A, B, C, D);
    float4 bv = ld4(bi + c);
    A = f4bias(A, bv); B = f4bias(B, bv); C = f4bias(C, bv); D = f4bias(D, bv);
    if (do_relu) { A = f4relu(A); B = f4relu(B); C = f4relu(C); D = f4relu(D); }
    if (ra < n) st4(Y + (size_t)ra * M + c, A);
    if (rb < n) st4(Y + (size_t)rb * M + c, B);
    if (rc < n) st4(Y + (size_t)rc * M + c, C);
    if (rd < n) st4(Y + (size_t)rd * M + c, D);
}

// ---------------- MFMA dense kernels ----------------

__device__ __forceinline__ f16x8 mk_af(const float* xr, int kb) {
    float4 v0 = ld4(xr + kb), v1 = ld4(xr + kb + 4);
    f16x8 af;
    af[0] = (_Float16)v0.x; af[1] = (_Float16)v0.y;
    af[2] = (_Float16)v0.z; af[3] = (_Float16)v0.w;
    af[4] = (_Float16)v1.x; af[5] = (_Float16)v1.y;
    af[6] = (_Float16)v1.z; af[7] = (_Float16)v1.w;
    return af;
}

// input stage: 3 weight sets, same X (K=64, M=128), bias only, fp32 out
__global__ __launch_bounds__(256)
void mfma_lin3_k(const float* __restrict__ X, const __half* __restrict__ WTin,
                 const float* __restrict__ b0, float* __restrict__ Y0,
                 const float* __restrict__ b1, float* __restrict__ Y1,
                 const float* __restrict__ b2, float* __restrict__ Y2,
                 int n, int gper) {
    constexpr int K = 64, CT = 8;
    int set = blockIdx.x / gper, blk = blockIdx.x % gper;
    const __half* WT = WTin + (size_t)set * 8192;
    const float* bi = set == 0 ? b0 : (set == 1 ? b1 : b2);
    float* Y = set == 0 ? Y0 : (set == 1 ? Y1 : Y2);
    int wave = threadIdx.x >> 6, lane = threadIdx.x & 63;
    int m = lane & 15, quad = lane >> 4;
    int row0 = blk * 64 + wave * 16;
    int arow = min(row0 + m, n - 1);
    const float* xr = X + (size_t)arow * K;
    f32x4 acc[CT];
#pragma unroll
    for (int ct = 0; ct < CT; ++ct) acc[ct] = (f32x4){0.f, 0.f, 0.f, 0.f};
#pragma unroll
    for (int k32 = 0; k32 < K / 32; ++k32) {
        int kb = k32 * 32 + quad * 8;
        f16x8 af = mk_af(xr, kb);
#pragma unroll
        for (int ct = 0; ct < CT; ++ct) {
            f16x8 bf = *reinterpret_cast<const f16x8*>(WT + (size_t)(ct * 16 + m) * K + kb);
            acc[ct] = __builtin_amdgcn_mfma_f32_16x16x32_f16(af, bf, acc[ct], 0, 0, 0);
        }
    }
#pragma unroll
    for (int ct = 0; ct < CT; ++ct) {
        int col = ct * 16 + m;
        float cb = bi[col];
#pragma unroll
        for (int reg = 0; reg < 4; ++reg) {
            int row = row0 + quad * 4 + reg;
            if (row < n) Y[(size_t)row * 128 + col] = acc[ct][reg] + cb;
        }
    }
}

// tail pair: two (X, WT, b[,bn]) sets, fp32 out
template <int K, int M>
__global__ __launch_bounds__(256)
void mfma_lin2_k(const float* __restrict__ X0, const __half* __restrict__ WT0,
                 const float* __restrict__ b0, const float* __restrict__ g0,
                 const float* __restrict__ bb0, float* __restrict__ Y0,
                 const float* __restrict__ X1, const __half* __restrict__ WT1,
                 const float* __restrict__ b1, const float* __restrict__ g1,
                 const float* __restrict__ bb1, float* __restrict__ Y1,
                 int n, int gper, int do_relu) {
    constexpr int CT = M / 16;
    bool s1 = blockIdx.x >= gper;
    int blk = s1 ? blockIdx.x - gper : blockIdx.x;
    const float* X = s1 ? X1 : X0;
    const __half* WT = s1 ? WT1 : WT0;
    const float* bi = s1 ? b1 : b0;
    const float* bg = s1 ? g1 : g0;
    const float* bb = s1 ? bb1 : bb0;
    float* Y = s1 ? Y1 : Y0;
    int wave = threadIdx.x >> 6, lane = threadIdx.x & 63;
    int m = lane & 15, quad = lane >> 4;
    int row0 = blk * 64 + wave * 16;
    int arow = min(row0 + m, n - 1);
    const float* xr = X + (size_t)arow * K;
    f32x4 acc[CT];
#pragma unroll
    for (int ct = 0; ct < CT; ++ct) acc[ct] = (f32x4){0.f, 0.f, 0.f, 0.f};
#pragma unroll
    for (int k32 = 0; k32 < K / 32; ++k32) {
        int kb = k32 * 32 + quad * 8;
        f16x8 af = mk_af(xr, kb);
#pragma unroll
        for (int ct = 0; ct < CT; ++ct) {
            f16x8 bf = *reinterpret_cast<const f16x8*>(WT + (size_t)(ct * 16 + m) * K + kb);
            acc[ct] = __builtin_amdgcn_mfma_f32_16x16x32_f16(af, bf, acc[ct], 0, 0, 0);
        }
    }
#pragma unroll
    for (int ct = 0; ct < CT; ++ct) {
        int col = ct * 16 + m;
        float cb = bi[col];
        float cg = bg ? bg[col] * RSQ_BN : 1.f;
        float cbb = bg ? bb[col] : 0.f;
#pragma unroll
        for (int reg = 0; reg < 4; ++reg) {
            int row = row0 + quad * 4 + reg;
            if (row < n) {
                float v = acc[ct][reg] + cb;
                if (do_relu) v = fmaxf(v, 0.f);
                if (bg) v = v * cg + cbb;
                Y[(size_t)row * M + col] = v;
            }
        }
    }
}

// final: blend(0.6*XA+0.4*XB) @ fin(K=128,M=64) -> relu -> bn -> @fin2 -> out[n,2]
__global__ __launch_bounds__(256)
void mfma_linF_k(const float* __restrict__ XA, const float* __restrict__ XB,
                 const __half* __restrict__ WT, const float* __restrict__ bi,
                 const float* __restrict__ bg, const float* __restrict__ bb,
                 const float* __restrict__ w2, const float* __restrict__ b2,
                 float* __restrict__ out, int n) {
    constexpr int K = 128, M = 64, CT = 4;
    int wave = threadIdx.x >> 6, lane = threadIdx.x & 63;
    int m = lane & 15, quad = lane >> 4;
    int row0 = blockIdx.x * 64 + wave * 16;
    int arow = min(row0 + m, n - 1);
    const float* xra = XA + (size_t)arow * K;
    const float* xrb = XB + (size_t)arow * K;
    f32x4 acc[CT];
#pragma unroll
    for (int ct = 0; ct < CT; ++ct) acc[ct] = (f32x4){0.f, 0.f, 0.f, 0.f};
#pragma unroll
    for (int k32 = 0; k32 < K / 32; ++k32) {
        int kb = k32 * 32 + quad * 8;
        float4 a0 = ld4(xra + kb), a1 = ld4(xra + kb + 4);
        float4 u0 = ld4(xrb + kb), u1 = ld4(xrb + kb + 4);
        f16x8 af;
        af[0] = (_Float16)(0.6f * a0.x + 0.4f * u0.x);
        af[1] = (_Float16)(0.6f * a0.y + 0.4f * u0.y);
        af[2] = (_Float16)(0.6f * a0.z + 0.4f * u0.z);
        af[3] = (_Float16)(0.6f * a0.w + 0.4f * u0.w);
        af[4] = (_Float16)(0.6f * a1.x + 0.4f * u1.x);
        af[5] = (_Float16)(0.6f * a1.y + 0.4f * u1.y);
        af[6] = (_Float16)(0.6f * a1.z + 0.4f * u1.z);
        af[7] = (_Float16)(0.6f * a1.w + 0.4f * u1.w);
#pragma unroll
        for (int ct = 0; ct < CT; ++ct) {
            f16x8 bf = *reinterpret_cast<const f16x8*>(WT + (size_t)(ct * 16 + m) * K + kb);
            acc[ct] = __builtin_amdgcn_mfma_f32_16x16x32_f16(af, bf, acc[ct], 0, 0, 0);
        }
    }
    float p0[4] = {0.f, 0.f, 0.f, 0.f}, p1[4] = {0.f, 0.f, 0.f, 0.f};
#pragma unroll
    for (int ct = 0; ct < CT; ++ct) {
        int col = ct * 16 + m;
        float cb = bi[col];
        float cg = bg[col] * RSQ_BN;
        float cbb = bb[col];
        float w20 = w2[2 * col], w21 = w2[2 * col + 1];
#pragma unroll
        for (int reg = 0; reg < 4; ++reg) {
            float v = fmaxf(acc[ct][reg] + cb, 0.f) * cg + cbb;
            p0[reg] += v * w20;
            p1[reg] += v * w21;
        }
    }
    for (int off = 1; off < 16; off <<= 1) {
#pragma unroll
        for (int reg = 0; reg < 4; ++reg) {
            p0[reg] += __shfl_xor(p0[reg], off);
            p1[reg] += __shfl_xor(p1[reg], off);
        }
    }
    if (m == 0) {
#pragma unroll
        for (int reg = 0; reg < 4; ++reg) {
            int row = row0 + quad * 4 + reg;
            if (row < n) {
                out[row * 2] = p0[reg] + b2[0];
                out[row * 2 + 1] = p1[reg] + b2[1];
            }
        }
    }
}

// ---------------- per-layer pair GEMM via MFMA (gcn dis-fold + gat attn dots) ----------------

__global__ __launch_bounds__(256)
void dual128_mfma_k(const float* __restrict__ Xg, const __half* __restrict__ WTg,
                    __half* __restrict__ Yg,
                    const float* __restrict__ Xa, const __half* __restrict__ WTa,
                    __half* __restrict__ Ya,
                    const float* __restrict__ dis,
                    const float* __restrict__ asrc, const float* __restrict__ adst,
                    float* __restrict__ avp, float* __restrict__ bvp,
                    int hh, int n, int gper) {
    bool gat = blockIdx.x >= gper;
    int blk = gat ? blockIdx.x - gper : blockIdx.x;
    const float* X = gat ? Xa : Xg;
    const __half* WT = gat ? WTa : WTg;
    __half* Y = gat ? Ya : Yg;
    int wave = threadIdx.x >> 6;
    int lane = threadIdx.x & 63;
    int m = lane & 15, quad = lane >> 4;
    int row0 = blk * 64 + wave * 16;
    int arow = min(row0 + m, n - 1);
    const float* xr = X + (size_t)arow * 128;
    f32x4 acc[8];
#pragma unroll
    for (int ct = 0; ct < 8; ++ct) acc[ct] = (f32x4){0.f, 0.f, 0.f, 0.f};
#pragma unroll
    for (int k32 = 0; k32 < 4; ++k32) {
        int kb = k32 * 32 + quad * 8;
        f16x8 af = mk_af(xr, kb);
#pragma unroll
        for (int ct = 0; ct < 8; ++ct) {
            f16x8 bf = *reinterpret_cast<const f16x8*>(WT + (size_t)(ct * 16 + m) * 128 + kb);
            acc[ct] = __builtin_amdgcn_mfma_f32_16x16x32_f16(af, bf, acc[ct], 0, 0, 0);
        }
    }
    if (!gat) {
#pragma unroll
        for (int reg = 0; reg < 4; ++reg) {
            int row = row0 + quad * 4 + reg;
            if (row < n) {
                float dv = dis[row];
#pragma unroll
                for (int ct = 0; ct < 8; ++ct)
                    Y[(size_t)row * 128 + ct * 16 + m] = (__half)(acc[ct][reg] * dv);
            }
        }
    } else {
        float cas[8], cad[8];
#pragma unroll
        for (int ct = 0; ct < 8; ++ct) {
            cas[ct] = asrc[ct * 16 + m];
            cad[ct] = adst[ct * 16 + m];
        }
        int ctph = 8 / hh;   // col-tiles per head
#pragma unroll
        for (int reg = 0; reg < 4; ++reg) {
            int row = row0 + quad * 4 + reg;
            bool valid = row < n;
            if (valid) {
#pragma unroll
                for (int ct = 0; ct < 8; ++ct)
                    Y[(size_t)row * 128 + ct * 16 + m] = (__half)acc[ct][reg];
            }
            for (int h = 0; h < hh; ++h) {
                float sa = 0.f, sd = 0.f;
                for (int j = 0; j < ctph; ++j) {
                    int ct = h * ctph + j;
                    sa += acc[ct][reg] * cas[ct];
                    sd += acc[ct][reg] * cad[ct];
                }
                for (int off = 1; off < 16; off <<= 1) {
                    sa += __shfl_xor(sa, off);
                    sd += __shfl_xor(sd, off);
                }
                if (m == 0 && valid) {
                    avp[row * hh + h] = sa;
                    bvp[row * hh + h] = sd;
                }
            }
        }
    }
}

// ---------------- fused sparse aggregation: one row-walk, BOTH tables, 4-edge groups ----------------
// 16 lanes/node, 8 cols (16B fp16) per lane per table; colidx software-pipelined.

__global__ __launch_bounds__(256)
void fused_gather_k(const int* __restrict__ rowptr, const int* __restrict__ colidx,
                    const float* __restrict__ dis,
                    const __half* __restrict__ Tg, const float* __restrict__ gbias,
                    const float* __restrict__ gbng, const float* __restrict__ gbnb,
                    const float* __restrict__ res, float* __restrict__ Yg,
                    const __half* __restrict__ Ta, const float* __restrict__ avp,
                    const float* __restrict__ bvp, const float* __restrict__ abias,
                    const float* __restrict__ abng, const float* __restrict__ abnb,
                    const float* __restrict__ fimp, float* __restrict__ Ya,
                    int n, int hh, int log2C) {
    int idx = blockIdx.x * 256 + threadIdx.x;
    int i = idx >> 4;
    if (i >= n) return;
    int c = (idx & 15) * 8;
    int h = c >> log2C;
    float ad = bvp[i * hh + h];
    int p0 = rowptr[i], p1 = rowptr[i + 1];
    float4 glo = f4z(), ghi = f4z();           // gcn accumulators (plain sum)
    float4 alo = f4z(), ahi = f4z();           // gat accumulators (online softmax)
    float m = -3.0e38f, s = 0.f;

#define GACC(qq)                                                                \
    {                                                                           \
        float4 t0 = h4f(make_uint2(qq.x, qq.y)), t1 = h4f(make_uint2(qq.z, qq.w)); \
        glo.x += t0.x; glo.y += t0.y; glo.z += t0.z; glo.w += t0.w;             \
        ghi.x += t1.x; ghi.y += t1.y; ghi.z += t1.z; ghi.w += t1.w;             \
    }
#define AACC(qq, ww)                                                            \
    {                                                                           \
        float4 t0 = h4f(make_uint2(qq.x, qq.y)), t1 = h4f(make_uint2(qq.z, qq.w)); \
        alo.x += t0.x * ww; alo.y += t0.y * ww; alo.z += t0.z * ww; alo.w += t0.w * ww; \
        ahi.x += t1.x * ww; ahi.y += t1.y * ww; ahi.z += t1.z * ww; ahi.w += t1.w * ww; \
    }

    int p = p0;
    int nfull = (p1 - p0) >> 2;
    int sx[4];
    if (nfull > 0) {
#pragma unroll
        for (int j = 0; j < 4; ++j) sx[j] = colidx[p + j];
    }
    for (int g = 0; g < nfull; ++g) {
        float e[4]; uint4 qg[4], qa[4];
#pragma unroll
        for (int j = 0; j < 4; ++j) e[j] = leaky02(avp[sx[j] * hh + h] + ad);
#pragma unroll
        for (int j = 0; j < 4; ++j)
            qg[j] = *reinterpret_cast<const uint4*>(Tg + (size_t)sx[j] * 128 + c);
#pragma unroll
        for (int j = 0; j < 4; ++j)
            qa[j] = *reinterpret_cast<const uint4*>(Ta + (size_t)sx[j] * 128 + c);
        // prefetch next group's indices while gathers are in flight
        int sn[4];
        int pn = p + 4;
        bool more = (g + 1) < nfull;
#pragma unroll
        for (int j = 0; j < 4; ++j) sn[j] = more ? colidx[pn + j] : 0;
#pragma unroll
        for (int j = 0; j < 4; ++j) GACC(qg[j])
        float mc = fmaxf(fmaxf(e[0], e[1]), fmaxf(e[2], e[3]));
        float mn = fmaxf(m, mc);
        float scale = expf(m - mn);
        alo = f4s(alo, scale);
        ahi = f4s(ahi, scale);
        float wsum = 0.f;
#pragma unroll
        for (int j = 0; j < 4; ++j) {
            float wj = expf(e[j] - mn);
            wsum += wj;
            AACC(qa[j], wj)
        }
        s = s * scale + wsum;
        m = mn;
        p = pn;
#pragma unroll
        for (int j = 0; j < 4; ++j) sx[j] = sn[j];
    }
    for (; p < p1; ++p) {
        int s0 = colidx[p];
        float e0 = leaky02(avp[s0 * hh + h] + ad);
        uint4 qg0 = *reinterpret_cast<const uint4*>(Tg + (size_t)s0 * 128 + c);
        uint4 qa0 = *reinterpret_cast<const uint4*>(Ta + (size_t)s0 * 128 + c);
        GACC(qg0)
        float mn = fmaxf(m, e0);
        float scale = expf(m - mn);
        float w0 = expf(e0 - mn);
        s = s * scale + w0;
        alo = f4s(alo, scale);
        ahi = f4s(ahi, scale);
        AACC(qa0, w0)
        m = mn;
    }

    // ---- GCN epilogue ----
    {
        float di = dis[i];
        float4 b0 = ld4(gbias + c), b1 = ld4(gbias + c + 4);
        glo = make_float4(glo.x * di + b0.x, glo.y * di + b0.y, glo.z * di + b0.z, glo.w * di + b0.w);
        ghi = make_float4(ghi.x * di + b1.x, ghi.y * di + b1.y, ghi.z * di + b1.z, ghi.w * di + b1.w);
        float4 g0 = ld4(gbng + c), g1 = ld4(gbng + c + 4);
        g0 = f4s(g0, RSQ_BN); g1 = f4s(g1, RSQ_BN);
        float4 h0 = ld4(gbnb + c), h1 = ld4(gbnb + c + 4);
        glo = f4relu(f4bn(glo, g0, h0));
        ghi = f4relu(f4bn(ghi, g1, h1));
        if (res) {
            float4 r0 = ld4(res + (size_t)i * 128 + c), r1 = ld4(res + (size_t)i * 128 + c + 4);
            glo = f4bias(glo, r0); ghi = f4bias(ghi, r1);
        }
        st4(Yg + (size_t)i * 128 + c, glo);
        st4(Yg + (size_t)i * 128 + c + 4, ghi);
    }
    // ---- GAT epilogue ----
    {
        float si = 1.f / (s + 1e-16f);
        float4 b0 = ld4(abias + c), b1 = ld4(abias + c + 4);
        alo = make_float4(alo.x * si + b0.x, alo.y * si + b0.y, alo.z * si + b0.z, alo.w * si + b0.w);
        ahi = make_float4(ahi.x * si + b1.x, ahi.y * si + b1.y, ahi.z * si + b1.z, ahi.w * si + b1.w);
        float4 g0 = ld4(abng + c), g1 = ld4(abng + c + 4);
        g0 = f4s(g0, RSQ_BN); g1 = f4s(g1, RSQ_BN);
        float4 h0 = ld4(abnb + c), h1 = ld4(abnb + c + 4);
        alo = f4bn(alo, g0, h0);
        ahi = f4bn(ahi, g1, h1);
        alo.x = alo.x > 0.f ? alo.x : expm1f(alo.x);
        alo.y = alo.y > 0.f ? alo.y : expm1f(alo.y);
        alo.z = alo.z > 0.f ? alo.z : expm1f(alo.z);
        alo.w = alo.w > 0.f ? alo.w : expm1f(alo.w);
        ahi.x = ahi.x > 0.f ? ahi.x : expm1f(ahi.x);
        ahi.y = ahi.y > 0.f ? ahi.y : expm1f(ahi.y);
        ahi.z = ahi.z > 0.f ? ahi.z : expm1f(ahi.z);
        ahi.w = ahi.w > 0.f ? ahi.w : expm1f(ahi.w);
        if (fimp) {
            float4 f0 = ld4(fimp + c), f1 = ld4(fimp + c + 4);
            alo = make_float4(alo.x * f0.x, alo.y * f0.y, alo.z * f0.z, alo.w * f0.w);
            ahi = make_float4(ahi.x * f1.x, ahi.y * f1.y, ahi.z * f1.z, ahi.w * f1.w);
        }
        st4(Ya + (size_t)i * 128 + c, alo);
        st4(Ya + (size_t)i * 128 + c + 4, ahi);
    }
#undef GACC
#undef AACC
}

// ---------------- host orchestration ----------------

static inline int cdiv(int a, int b) { return (a + b - 1) / b; }

extern "C" void kernel_launch(void* const* d_in, const int* in_sizes, int n_in,
                              void* d_out, int out_size, void* d_ws, size_t ws_size,
                              hipStream_t stream) {
    const float* x       = (const float*)d_in[0];
    const int*   ei      = (const int*)d_in[1];
    const float* gcn_in_w = (const float*)d_in[2];
    const float* gcn_in_b = (const float*)d_in[3];
    const float* gcn_res_w = (const float*)d_in[4];
    const float* gcn_res_b = (const float*)d_in[5];
    const float* gcn_w   = (const float*)d_in[6];
    const float* gcn_b   = (const float*)d_in[7];
    const float* gcn_bn_g = (const float*)d_in[8];
    const float* gcn_bn_b = (const float*)d_in[9];
    const float* gcn_c1w = (const float*)d_in[10];
    const float* gcn_c1b = (const float*)d_in[11];
    const float* gcn_c2w = (const float*)d_in[12];
    const float* gcn_c2b = (const float*)d_in[13];
    const float* gcn_c3w = (const float*)d_in[14];
    const float* gcn_c3b = (const float*)d_in[15];
    const float* gat_in_w = (const float*)d_in[16];
    const float* gat_in_b = (const float*)d_in[17];
    const float* gat_w   = (const float*)d_in[18];
    const float* gat_asrc = (const float*)d_in[19];
    const float* gat_adst = (const float*)d_in[20];
    const float* gat_b   = (const float*)d_in[21];
    const float* gat_bn_g = (const float*)d_in[22];
    const float* gat_bn_b = (const float*)d_in[23];
    const float* feat_imp = (const float*)d_in[24];
    const float* gat_c1w = (const float*)d_in[25];
    const float* gat_c1b = (const float*)d_in[26];
    const float* gat_cbn_g = (const float*)d_in[27];
    const float* gat_cbn_b = (const float*)d_in[28];
    const float* gat_c2w = (const float*)d_in[29];
    const float* gat_c2b = (const float*)d_in[30];
    const float* gat_c3w = (const float*)d_in[31];
    const float* gat_c3b = (const float*)d_in[32];
    const float* fin_w   = (const float*)d_in[33];
    const float* fin_b   = (const float*)d_in[34];
    const float* fin_bn_g = (const float*)d_in[35];
    const float* fin_bn_b = (const float*)d_in[36];
    const float* fin2_w  = (const float*)d_in[37];
    const float* fin2_b  = (const float*)d_in[38];

    const int N = in_sizes[0] / 64;
    const int E = in_sizes[1] / 2;
    const int EN = E + N;
    const int* esrc = ei;
    const int* edst = ei + E;

    // workspace carve (256B aligned)
    char* wp = (char*)d_ws;
    auto alloc = [&](size_t bytes) -> void* {
        void* p = (void*)wp;
        wp += (bytes + 255) & ~(size_t)255;
        return p;
    };
    int* cnt    = (int*)alloc((size_t)N * 4);
    int* rowptr = (int*)alloc((size_t)(N + 1) * 4);
    int* cursor = (int*)alloc((size_t)N * 4);
    int* bsum   = (int*)alloc((size_t)256 * 4);
    int* colidx = (int*)alloc((size_t)EN * 4);
    float* dis  = (float*)alloc((size_t)N * 4);
    float* A    = (float*)alloc((size_t)N * 128 * 4);   // gcn ping / GOUT reuse
    float* B    = (float*)alloc((size_t)N * 128 * 4);   // gcn pong
    float* G    = (float*)alloc((size_t)N * 128 * 4);   // gat ping / AOUT reuse
    float* H    = (float*)alloc((size_t)N * 128 * 4);   // gat pong
    float* R    = (float*)alloc((size_t)N * 128 * 4);   // gcn residual
    __half* Th1 = (__half*)alloc((size_t)N * 128 * 2);  // aliased as h1g after layers
    __half* Th2 = (__half*)alloc((size_t)N * 128 * 2);  // aliased as h1a after layers
    float* h2g  = (float*)alloc((size_t)N * 32 * 4);
    float* h2a  = (float*)alloc((size_t)N * 32 * 4);
    float* avv  = (float*)alloc((size_t)N * 4 * 4);
    float* bvv  = (float*)alloc((size_t)N * 4 * 4);
    __half* WTin = (__half*)alloc((size_t)3 * 8192 * 2);
    __half* WTg  = (__half*)alloc((size_t)3 * 16384 * 2);
    __half* WTa  = (__half*)alloc((size_t)3 * 16384 * 2);
    __half* WTc1 = (__half*)alloc((size_t)2 * 8192 * 2);
    __half* WTc3 = (__half*)alloc((size_t)2 * 4096 * 2);
    __half* WTfin = (__half*)alloc((size_t)8192 * 2);
    float* h1g = (float*)Th1;   // N*64*4 == N*128*2 bytes
    float* h1a = (float*)Th2;

    // ---- CSR build + all-weight transpose ----
    const int nScanB = cdiv(N, 256);
    zero_i32_k<<<cdiv(N, 256), 256, 0, stream>>>(cnt, N);
    hist_k<<<cdiv(EN, 256), 256, 0, stream>>>(edst, cnt, E, EN);
    scanA_k<<<nScanB, 256, 0, stream>>>(cnt, rowptr, bsum, N);
    scanB_k<<<1, 256, 0, stream>>>(bsum, nScanB);
    scanC_k<<<nScanB, 256, 0, stream>>>(cnt, bsum, rowptr, cursor, dis, N, EN);
    scatter_k<<<cdiv(EN, 256), 256, 0, stream>>>(esrc, edst, cursor, colidx, E, EN);
    wtx_all_k<<<608, 256, 0, stream>>>(gcn_in_w, gcn_res_w, gat_in_w, gcn_w, gat_w,
                                       gcn_c1w, gat_c1w, gcn_c3w, gat_c3w, fin_w,
                                       WTin, WTg, WTa, WTc1, WTc3, WTfin);

    const int g64r  = cdiv(N, 64);    // mfma kernels: 64 rows/block
    const int g128r = cdiv(N, 128);   // fp32 tail M=32
    const int gG    = cdiv(N, 16);    // gather: 16 nodes/block

    // ---- input stage: gcn_in -> A, gcn_res -> R, gat_in -> G ----
    mfma_lin3_k<<<3 * g64r, 256, 0, stream>>>(x, WTin, gcn_in_b, A, gcn_res_b, R,
                                              gat_in_b, G, N, g64r);

    // ---- 3 layers, both branches in lockstep ----
    const int heads_arr[3] = {4, 4, 1};
    float* gcur = A; float* gnxt = B;
    float* acur = G; float* anxt = H;
    for (int i = 0; i < 3; ++i) {
        int hh = heads_arr[i];
        int log2C = (hh == 4) ? 5 : 7;
        dual128_mfma_k<<<2 * g64r, 256, 0, stream>>>(gcur, WTg + (size_t)i * 16384, Th1,
                                                     acur, WTa + (size_t)i * 16384, Th2, dis,
                                                     gat_asrc + i * 128, gat_adst + i * 128,
                                                     avv, bvv, hh, N, g64r);
        fused_gather_k<<<gG, 256, 0, stream>>>(rowptr, colidx, dis,
                                               Th1, gcn_b + i * 128, gcn_bn_g + i * 128,
                                               gcn_bn_b + i * 128, (i == 1) ? R : nullptr, gnxt,
                                               Th2, avv, bvv, gat_b + i * 128,
                                               gat_bn_g + i * 128, gat_bn_b + i * 128,
                                               (i == 2) ? feat_imp : nullptr, anxt,
                                               N, hh, log2C);
        float* t = gcur; gcur = gnxt; gnxt = t;
        t = acur; acur = anxt; anxt = t;
    }
    // gcur = gcn final xp (B), acur = gat final xg (H)

    // ---- MLP tails ----  (h1g/h1a alias Th1/Th2 — Th no longer needed)
    mfma_lin2_k<128, 64><<<2 * g64r, 256, 0, stream>>>(
        gcur, WTc1, gcn_c1b, nullptr, nullptr, h1g,
        acur, WTc1 + 8192, gat_c1b, gat_cbn_g, gat_cbn_b, h1a, N, g64r, 1);
    tail2_k<64, 32><<<2 * g128r, 256, 0, stream>>>(
        h1g, gcn_c2w, gcn_c2b, h2g,
        h1a, gat_c2w, gat_c2b, h2a, N, g128r, 1);
    mfma_lin2_k<32, 128><<<2 * g64r, 256, 0, stream>>>(
        h2g, WTc3, gcn_c3b, nullptr, nullptr, A,
        h2a, WTc3 + 4096, gat_c3b, nullptr, nullptr, G, N, g64r, 0);

    // ---- fusion tail: blend + fin linear + bn + classifier ----
    mfma_linF_k<<<g64r, 256, 0, stream>>>(A, G, WTfin, fin_b, fin_bn_g, fin_bn_b,
                                          fin2_w, fin2_b, (float*)d_out, N);
}